// Round 2
// baseline (1250.097 us; speedup 1.0000x reference)
//
#include <hip/hip_runtime.h>
#include <hip/hip_bf16.h>
#include <math.h>

typedef __bf16 bf16x8 __attribute__((ext_vector_type(8)));
typedef float f32x4 __attribute__((ext_vector_type(4)));

// ---------------- CSR build ----------------

__global__ void count_deg_kernel(const int* __restrict__ ei, int E, int* __restrict__ cnt) {
  int stride = gridDim.x * blockDim.x;
  for (int e = blockIdx.x * blockDim.x + threadIdx.x; e < E; e += stride)
    atomicAdd(&cnt[ei[E + e]], 1);
}

__global__ void dinv_kernel(const int* __restrict__ cnt, float* __restrict__ dinv, int n) {
  int stride = gridDim.x * blockDim.x;
  for (int i = blockIdx.x * blockDim.x + threadIdx.x; i < n; i += stride)
    dinv[i] = rsqrtf((float)cnt[i] + 1.0f);  // +1 self-loop
}

__global__ __launch_bounds__(256) void scan1_kernel(const int* __restrict__ cnt,
                                                    int* __restrict__ row_ptr,
                                                    int* __restrict__ bsums, int n) {
  __shared__ int sdata[256];
  int t = threadIdx.x;
  int base = blockIdx.x * 1024;
  int v[4]; int s = 0;
#pragma unroll
  for (int c = 0; c < 4; ++c) {
    int idx = base + t * 4 + c;
    v[c] = (idx < n) ? cnt[idx] : 0;
    s += v[c];
  }
  sdata[t] = s;
  __syncthreads();
  for (int off = 1; off < 256; off <<= 1) {
    int y = (t >= off) ? sdata[t - off] : 0;
    __syncthreads();
    sdata[t] += y;
    __syncthreads();
  }
  int run = sdata[t] - s;
#pragma unroll
  for (int c = 0; c < 4; ++c) {
    int idx = base + t * 4 + c;
    if (idx < n) row_ptr[idx] = run;
    run += v[c];
  }
  if (t == 255) bsums[blockIdx.x] = sdata[255];
}

__global__ void scan2_kernel(int* bsums, int nb) {
  if (blockIdx.x == 0 && threadIdx.x == 0) {
    int run = 0;
    for (int i = 0; i < nb; ++i) { int v = bsums[i]; bsums[i] = run; run += v; }
  }
}

__global__ void scan3_kernel(int* __restrict__ row_ptr, const int* __restrict__ bsums,
                             int* __restrict__ pos, int n, int E) {
  int stride = gridDim.x * blockDim.x;
  int gid0 = blockIdx.x * blockDim.x + threadIdx.x;
  for (int i = gid0; i < n; i += stride) {
    int v = row_ptr[i] + bsums[i >> 10];
    row_ptr[i] = v;
    pos[i] = v;
  }
  if (gid0 == 0) row_ptr[n] = E;
}

__global__ void fill_csr_kernel(const int* __restrict__ ei, int E,
                                int* __restrict__ pos, int* __restrict__ col_src) {
  int stride = gridDim.x * blockDim.x;
  for (int e = blockIdx.x * blockDim.x + threadIdx.x; e < E; e += stride) {
    int s = ei[e];
    int d = ei[E + e];
    int p2 = atomicAdd(&pos[d], 1);
    col_src[p2] = s;
  }
}

// ---------------- bf16 hi/lo split helpers ----------------

__global__ void split_w_kernel(const float* __restrict__ cw, const float* __restrict__ lw,
                               int cn, int total, __bf16* __restrict__ whi,
                               __bf16* __restrict__ wlo) {
  int stride = gridDim.x * blockDim.x;
  for (int i = blockIdx.x * blockDim.x + threadIdx.x; i < total; i += stride) {
    float v = (i < cn) ? cw[i] : lw[i - cn];
    __bf16 hi = (__bf16)v;
    whi[i] = hi;
    wlo[i] = (__bf16)(v - (float)hi);
  }
}

__global__ void init_h_kernel(const float* __restrict__ x, __bf16* __restrict__ h_hi,
                              __bf16* __restrict__ h_lo, long total) {
  long stride = (long)gridDim.x * blockDim.x;
  for (long i = blockIdx.x * (long)blockDim.x + threadIdx.x; i < total; i += stride) {
    float v = x[i];
    __bf16 hi = (__bf16)v;
    h_hi[i] = hi;
    h_lo[i] = (__bf16)(v - (float)hi);
  }
}

// ---------------- split-bf16 MFMA GEMM ----------------
// C[n x 128] = rowscale(A @ W^T) + bias (+C)   A = a_hi + a_lo (bf16 pair, [n][128])
// W = w_hi + w_lo (bf16 pair, row-major [128][ldb], row = output neuron, k-contiguous)
// Per wave: 16-row strip x 128 cols, K=128 in 4 chunks of 32.
// Fragment layouts (verified gfx950): A: row=l&15, k=(l>>4)*8+j; B: col=l&15, k=(l>>4)*8+j;
// D: col=l&15, row=(l>>4)*4+reg.
__global__ __launch_bounds__(256) void gemm_mfma_kernel(
    const __bf16* __restrict__ a_hi, const __bf16* __restrict__ a_lo,
    const __bf16* __restrict__ w_hi, const __bf16* __restrict__ w_lo, int ldb,
    float* __restrict__ C, const float* __restrict__ row_scale,
    const float* __restrict__ bias, int accum, int n) {
  int t = threadIdx.x;
  int wv = t >> 6;
  int l = t & 63;
  int r = l & 15;
  int g = l >> 4;
  int row0 = blockIdx.x * 64 + wv * 16;
  int arow = row0 + r;
  if (arow >= n) arow = n - 1;

  f32x4 acc[8];
#pragma unroll
  for (int i = 0; i < 8; ++i) acc[i] = (f32x4){0.f, 0.f, 0.f, 0.f};

  const __bf16* ah_base = a_hi + (long)arow * 128 + g * 8;
  const __bf16* al_base = a_lo + (long)arow * 128 + g * 8;

#pragma unroll
  for (int kc = 0; kc < 4; ++kc) {
    bf16x8 ah = *(const bf16x8*)(ah_base + kc * 32);
    bf16x8 al = *(const bf16x8*)(al_base + kc * 32);
    const __bf16* wph = w_hi + (long)r * ldb + kc * 32 + g * 8;
    const __bf16* wpl = w_lo + (long)r * ldb + kc * 32 + g * 8;
#pragma unroll
    for (int nt = 0; nt < 8; ++nt) {
      bf16x8 bh = *(const bf16x8*)(wph + (long)nt * 16 * ldb);
      bf16x8 bl = *(const bf16x8*)(wpl + (long)nt * 16 * ldb);
      acc[nt] = __builtin_amdgcn_mfma_f32_16x16x32_bf16(ah, bh, acc[nt], 0, 0, 0);
      acc[nt] = __builtin_amdgcn_mfma_f32_16x16x32_bf16(al, bh, acc[nt], 0, 0, 0);
      acc[nt] = __builtin_amdgcn_mfma_f32_16x16x32_bf16(ah, bl, acc[nt], 0, 0, 0);
    }
  }

  int orow0 = row0 + g * 4;
  float rs[4];
#pragma unroll
  for (int q = 0; q < 4; ++q) {
    int gr = orow0 + q;
    rs[q] = row_scale ? ((gr < n) ? row_scale[gr] : 0.f) : 1.0f;
  }
#pragma unroll
  for (int nt = 0; nt < 8; ++nt) {
    int col = nt * 16 + r;
    float bv = bias ? bias[col] : 0.f;
#pragma unroll
    for (int q = 0; q < 4; ++q) {
      int gr = orow0 + q;
      if (gr < n) {
        float* cp = C + (long)gr * 128 + col;
        float v = acc[nt][q] * rs[q] + bv;
        if (accum) v += *cp;
        *cp = v;
      }
    }
  }
}

// ---------------- aggregate (gather segment-sum, 8-wide MLP) ----------------
// h = elu(dinv[i]*(sum_in hw[src] + hw[i]) + b) + h   (h kept as bf16 hi/lo pair)
__global__ __launch_bounds__(128) void aggregate_kernel(
    const float* __restrict__ hw, const int* __restrict__ col_src,
    const int* __restrict__ row_ptr, const float* __restrict__ dinv,
    const float* __restrict__ bias, __bf16* __restrict__ h_hi,
    __bf16* __restrict__ h_lo, int n) {
  int i = blockIdx.x;
  int d = threadIdx.x;
  long base = (long)i * 128 + d;
  float acc = hw[base];  // self-loop (hw already dinv[row]-scaled)
  int e0 = row_ptr[i], e1 = row_ptr[i + 1];
  int e = e0;
  for (; e + 8 <= e1; e += 8) {
    int s0 = col_src[e + 0], s1 = col_src[e + 1], s2 = col_src[e + 2], s3 = col_src[e + 3];
    int s4 = col_src[e + 4], s5 = col_src[e + 5], s6 = col_src[e + 6], s7 = col_src[e + 7];
    float v0 = hw[(long)s0 * 128 + d], v1 = hw[(long)s1 * 128 + d];
    float v2 = hw[(long)s2 * 128 + d], v3 = hw[(long)s3 * 128 + d];
    float v4 = hw[(long)s4 * 128 + d], v5 = hw[(long)s5 * 128 + d];
    float v6 = hw[(long)s6 * 128 + d], v7 = hw[(long)s7 * 128 + d];
    acc += ((v0 + v1) + (v2 + v3)) + ((v4 + v5) + (v6 + v7));
  }
  for (; e + 2 <= e1; e += 2) {
    int s0 = col_src[e + 0], s1 = col_src[e + 1];
    float v0 = hw[(long)s0 * 128 + d], v1 = hw[(long)s1 * 128 + d];
    acc += v0 + v1;
  }
  if (e < e1) acc += hw[(long)col_src[e] * 128 + d];

  float xv = fmaf(acc, dinv[i], bias[d]);
  float v = (xv > 0.f) ? xv : expm1f(xv);
  float hv = (float)h_hi[base] + (float)h_lo[base] + v;
  __bf16 hi = (__bf16)hv;
  h_hi[base] = hi;
  h_lo[base] = (__bf16)(hv - (float)hi);
}

// ---------------- launch ----------------

extern "C" void kernel_launch(void* const* d_in, const int* in_sizes, int n_in,
                              void* d_out, int out_size, void* d_ws, size_t ws_size,
                              hipStream_t stream) {
  const float* x      = (const float*)d_in[0];
  const int*   ei     = (const int*)d_in[1];
  const float* conv_w = (const float*)d_in[2];
  const float* conv_b = (const float*)d_in[3];
  const float* lin_w  = (const float*)d_in[4];
  const float* lin_b  = (const float*)d_in[5];
  float* out = (float*)d_out;

  const int n = in_sizes[0] / 128;
  const int E = in_sizes[1] / 2;
  const int L = in_sizes[2] / (128 * 128);
  const int nb = (n + 1023) / 1024;
  const int cn = L * 128 * 128;            // conv weight elements
  const int wn = cn + in_sizes[4];         // + lin weight elements

  char* p = (char*)d_ws;
  auto carve = [&](size_t bytes) {
    char* r = p;
    p += (bytes + 255) & ~(size_t)255;
    return r;
  };
  int*    cnt     = (int*)carve((size_t)n * 4);
  int*    row_ptr = (int*)carve((size_t)(n + 1) * 4);
  int*    pos     = (int*)carve((size_t)n * 4);
  int*    bsums   = (int*)carve((size_t)nb * 4);
  int*    col_src = (int*)carve((size_t)E * 4);
  float*  dinv    = (float*)carve((size_t)n * 4);
  float*  hw      = (float*)carve((size_t)n * 128 * 4);
  __bf16* h_hi    = (__bf16*)carve((size_t)n * 128 * 2);
  __bf16* h_lo    = (__bf16*)carve((size_t)n * 128 * 2);
  __bf16* w_hi    = (__bf16*)carve((size_t)wn * 2);
  __bf16* w_lo    = (__bf16*)carve((size_t)wn * 2);
  __bf16* lw_hi   = w_hi + cn;
  __bf16* lw_lo   = w_lo + cn;

  // --- degree + CSR build (reused across all layers) ---
  hipMemsetAsync(cnt, 0, (size_t)n * 4, stream);
  count_deg_kernel<<<2048, 256, 0, stream>>>(ei, E, cnt);
  dinv_kernel<<<(n + 255) / 256, 256, 0, stream>>>(cnt, dinv, n);
  scan1_kernel<<<nb, 256, 0, stream>>>(cnt, row_ptr, bsums, n);
  scan2_kernel<<<1, 64, 0, stream>>>(bsums, nb);
  scan3_kernel<<<(n + 255) / 256, 256, 0, stream>>>(row_ptr, bsums, pos, n, E);
  fill_csr_kernel<<<2048, 256, 0, stream>>>(ei, E, pos, col_src);

  // --- weight + feature splits ---
  split_w_kernel<<<(wn + 255) / 256, 256, 0, stream>>>(conv_w, lin_w, cn, wn, w_hi, w_lo);
  init_h_kernel<<<2048, 256, 0, stream>>>(x, h_hi, h_lo, (long)n * 128);

  int gblocks = (n + 63) / 64;
  // out = x @ lin_w_block0^T + lin_b
  gemm_mfma_kernel<<<gblocks, 256, 0, stream>>>(h_hi, h_lo, lw_hi, lw_lo, 512,
                                                out, nullptr, lin_b, 0, n);
  for (int l = 0; l < L; ++l) {
    // hw = (h @ Wl^T) * dinv[row]
    gemm_mfma_kernel<<<gblocks, 256, 0, stream>>>(
        h_hi, h_lo, w_hi + (size_t)l * 128 * 128, w_lo + (size_t)l * 128 * 128, 128,
        hw, dinv, nullptr, 0, n);
    // h = elu(dinv*(sum_in hw + hw_self) + b) + h
    aggregate_kernel<<<n, 128, 0, stream>>>(hw, col_src, row_ptr, dinv,
                                            conv_b + (size_t)l * 128, h_hi, h_lo, n);
    // out += h @ lin_w_block_{l+1}^T
    gemm_mfma_kernel<<<gblocks, 256, 0, stream>>>(
        h_hi, h_lo, lw_hi + (size_t)(l + 1) * 128, lw_lo + (size_t)(l + 1) * 128, 512,
        out, nullptr, nullptr, 1, n);
  }
}

// Round 3
// 1003.385 us; speedup vs baseline: 1.2459x; 1.2459x over previous
//
#include <hip/hip_runtime.h>
#include <hip/hip_bf16.h>
#include <math.h>

typedef __bf16 bf16x8 __attribute__((ext_vector_type(8)));
typedef float f32x4 __attribute__((ext_vector_type(4)));
typedef unsigned int uint32;
typedef unsigned short ushort16;

#define TILE1 2048  // edges per block in pass-1 kernels

__device__ inline float bfl(uint32 v) { return __uint_as_float(v << 16); }
__device__ inline float bfh(uint32 v) { return __uint_as_float(v & 0xffff0000u); }
__device__ inline ushort16 f2bf(float f) {
  __bf16 b = (__bf16)f;
  return __builtin_bit_cast(ushort16, b);
}
__device__ inline float bf2f(ushort16 u) { return __uint_as_float(((uint32)u) << 16); }

// ---------------- MSD bucket sort CSR build (no global atomics) ----------------
// pass 1: bucket by dst>>9 ; pass 2: per bucket, by dst&511 -> col_src, row_ptr, dinv

__global__ __launch_bounds__(256) void hist1_kernel(const int* __restrict__ ei, int E,
                                                    int nT1, int nb1, int* __restrict__ histT) {
  __shared__ int h[512];
  int t = threadIdx.x;
  for (int b = t; b < 512; b += 256) h[b] = 0;
  __syncthreads();
  int base = blockIdx.x * TILE1;
  int end = min(base + TILE1, E);
  for (int e = base + t; e < end; e += 256) {
    int d = ei[E + e];
    atomicAdd(&h[d >> 9], 1);
  }
  __syncthreads();
  for (int b = t; b < nb1; b += 256) histT[b * nT1 + blockIdx.x] = h[b];
}

// generic chunked exclusive scan
__global__ __launch_bounds__(256) void scan1_kernel(const int* __restrict__ in,
                                                    int* __restrict__ out,
                                                    int* __restrict__ bsums, int m) {
  __shared__ int sdata[256];
  int t = threadIdx.x;
  int base = blockIdx.x * 1024;
  int v[4]; int s = 0;
#pragma unroll
  for (int c = 0; c < 4; ++c) {
    int idx = base + t * 4 + c;
    v[c] = (idx < m) ? in[idx] : 0;
    s += v[c];
  }
  sdata[t] = s;
  __syncthreads();
  for (int off = 1; off < 256; off <<= 1) {
    int y = (t >= off) ? sdata[t - off] : 0;
    __syncthreads();
    sdata[t] += y;
    __syncthreads();
  }
  int run = sdata[t] - s;
#pragma unroll
  for (int c = 0; c < 4; ++c) {
    int idx = base + t * 4 + c;
    if (idx < m) out[idx] = run;
    run += v[c];
  }
  if (t == 255) bsums[blockIdx.x] = sdata[255];
}

__global__ void scan2_kernel(int* bsums, int nb) {
  if (threadIdx.x == 0 && blockIdx.x == 0) {
    int run = 0;
    for (int i = 0; i < nb; ++i) { int v = bsums[i]; bsums[i] = run; run += v; }
  }
}

__global__ void scan_add_kernel(int* __restrict__ out, const int* __restrict__ bsums, int m) {
  int stride = gridDim.x * blockDim.x;
  for (int i = blockIdx.x * blockDim.x + threadIdx.x; i < m; i += stride)
    out[i] += bsums[i >> 10];
}

__global__ __launch_bounds__(256) void scatter1_kernel(const int* __restrict__ ei, int E,
                                                       int nT1, int nb1,
                                                       const int* __restrict__ histS,
                                                       int* __restrict__ keyT,
                                                       int* __restrict__ srcT) {
  __shared__ int base[512];
  int t = threadIdx.x;
  for (int b = t; b < nb1; b += 256) base[b] = histS[b * nT1 + blockIdx.x];
  __syncthreads();
  int s0 = blockIdx.x * TILE1;
  int end = min(s0 + TILE1, E);
  for (int e = s0 + t; e < end; e += 256) {
    int d = ei[E + e];
    int s = ei[e];
    int p = atomicAdd(&base[d >> 9], 1);  // LDS atomic
    keyT[p] = d;
    srcT[p] = s;
  }
}

__global__ __launch_bounds__(256) void pass2_kernel(
    const int* __restrict__ keyT, const int* __restrict__ srcT,
    const int* __restrict__ histS, int nT1, int nb1, int E, int n,
    int* __restrict__ col_src, int* __restrict__ row_ptr, float* __restrict__ dinv) {
  __shared__ int hist[512];
  __shared__ int offs[512];
  __shared__ int sdata[256];
  int b = blockIdx.x;
  int t = threadIdx.x;
  int bstart = histS[b * nT1];
  int bend = (b + 1 < nb1) ? histS[(b + 1) * nT1] : E;
  for (int i = t; i < 512; i += 256) hist[i] = 0;
  __syncthreads();
  for (int e = bstart + t; e < bend; e += 256)
    atomicAdd(&hist[keyT[e] & 511], 1);
  __syncthreads();
  // exclusive scan hist[512] -> offs[512]
  int s2 = hist[2 * t] + hist[2 * t + 1];
  sdata[t] = s2;
  __syncthreads();
  for (int off = 1; off < 256; off <<= 1) {
    int y = (t >= off) ? sdata[t - off] : 0;
    __syncthreads();
    sdata[t] += y;
    __syncthreads();
  }
  int excl = sdata[t] - s2;
  offs[2 * t] = excl;
  offs[2 * t + 1] = excl + hist[2 * t];
  __syncthreads();
  // row_ptr + dinv (bin counts are exactly the in-degrees)
  for (int i = t; i < 512; i += 256) {
    int node = (b << 9) + i;
    if (node < n) {
      row_ptr[node] = bstart + offs[i];
      dinv[node] = rsqrtf((float)hist[i] + 1.0f);  // +1 self-loop
    }
  }
  __syncthreads();
  // scatter (offs become cursors; in-bucket order arbitrary — fine for segment-sum)
  for (int e = bstart + t; e < bend; e += 256) {
    int d = keyT[e];
    int s = srcT[e];
    int p = atomicAdd(&offs[d & 511], 1);  // LDS atomic
    col_src[bstart + p] = s;
  }
}

__global__ void finalize_rowptr_kernel(int* row_ptr, int n, int E) {
  if (threadIdx.x == 0 && blockIdx.x == 0) row_ptr[n] = E;
}

// ---------------- bf16 hi/lo split helpers ----------------

__global__ void split_w_kernel(const float* __restrict__ cw, const float* __restrict__ lw,
                               int cn, int total, __bf16* __restrict__ whi,
                               __bf16* __restrict__ wlo) {
  int stride = gridDim.x * blockDim.x;
  for (int i = blockIdx.x * blockDim.x + threadIdx.x; i < total; i += stride) {
    float v = (i < cn) ? cw[i] : lw[i - cn];
    __bf16 hi = (__bf16)v;
    whi[i] = hi;
    wlo[i] = (__bf16)(v - (float)hi);
  }
}

__global__ void init_h_kernel(const float* __restrict__ x, __bf16* __restrict__ h_hi,
                              __bf16* __restrict__ h_lo, long total) {
  long stride = (long)gridDim.x * blockDim.x;
  for (long i = blockIdx.x * (long)blockDim.x + threadIdx.x; i < total; i += stride) {
    float v = x[i];
    __bf16 hi = (__bf16)v;
    h_hi[i] = hi;
    h_lo[i] = (__bf16)(v - (float)hi);
  }
}

// ---------------- split-bf16 MFMA GEMM ----------------
// Per wave: 16-row strip x 128 cols, K=128 in 4 chunks of 32.
// A: row=l&15, k=(l>>4)*8+j ; B: col=l&15 ; D: col=l&15, row=(l>>4)*4+reg.
__global__ __launch_bounds__(256) void gemm_mfma_kernel(
    const __bf16* __restrict__ a_hi, const __bf16* __restrict__ a_lo,
    const __bf16* __restrict__ w_hi, const __bf16* __restrict__ w_lo, int ldb,
    float* __restrict__ C, ushort16* __restrict__ Cb,
    const float* __restrict__ row_scale, const float* __restrict__ bias,
    int accum, int nterms, int n) {
  int t = threadIdx.x;
  int wv = t >> 6;
  int l = t & 63;
  int r = l & 15;
  int g = l >> 4;
  int row0 = blockIdx.x * 64 + wv * 16;
  int arow = row0 + r;
  if (arow >= n) arow = n - 1;

  f32x4 acc[8];
#pragma unroll
  for (int i = 0; i < 8; ++i) acc[i] = (f32x4){0.f, 0.f, 0.f, 0.f};

  const __bf16* ah_base = a_hi + (long)arow * 128 + g * 8;
  const __bf16* al_base = a_lo + (long)arow * 128 + g * 8;

#pragma unroll
  for (int kc = 0; kc < 4; ++kc) {
    bf16x8 ah = *(const bf16x8*)(ah_base + kc * 32);
    bf16x8 al = *(const bf16x8*)(al_base + kc * 32);
    const __bf16* wph = w_hi + (long)r * ldb + kc * 32 + g * 8;
    const __bf16* wpl = w_lo + (long)r * ldb + kc * 32 + g * 8;
#pragma unroll
    for (int nt = 0; nt < 8; ++nt) {
      bf16x8 bh = *(const bf16x8*)(wph + (long)nt * 16 * ldb);
      acc[nt] = __builtin_amdgcn_mfma_f32_16x16x32_bf16(ah, bh, acc[nt], 0, 0, 0);
      if (nterms > 1)
        acc[nt] = __builtin_amdgcn_mfma_f32_16x16x32_bf16(al, bh, acc[nt], 0, 0, 0);
      if (nterms > 2) {
        bf16x8 bl = *(const bf16x8*)(wpl + (long)nt * 16 * ldb);
        acc[nt] = __builtin_amdgcn_mfma_f32_16x16x32_bf16(ah, bl, acc[nt], 0, 0, 0);
      }
    }
  }

  int orow0 = row0 + g * 4;
  float rs[4];
#pragma unroll
  for (int q = 0; q < 4; ++q) {
    int gr = orow0 + q;
    rs[q] = row_scale ? ((gr < n) ? row_scale[gr] : 0.f) : 1.0f;
  }
#pragma unroll
  for (int nt = 0; nt < 8; ++nt) {
    int col = nt * 16 + r;
    float bv = bias ? bias[col] : 0.f;
#pragma unroll
    for (int q = 0; q < 4; ++q) {
      int gr = orow0 + q;
      if (gr < n) {
        float v = acc[nt][q] * rs[q] + bv;
        if (Cb) {
          Cb[(long)gr * 128 + col] = f2bf(v);
        } else {
          float* cp = C + (long)gr * 128 + col;
          if (accum) v += *cp;
          *cp = v;
        }
      }
    }
  }
}

// ---------------- aggregate: one wave per node, bf16 hw gather ----------------
// h = elu(dinv[i]*(sum_in hw[src] + hw[i]) + b) + h   (h kept as bf16 hi/lo pair)
__global__ __launch_bounds__(256) void aggregate_kernel(
    const uint32* __restrict__ hw2, const int* __restrict__ col_src,
    const int* __restrict__ row_ptr, const float* __restrict__ dinv,
    const float* __restrict__ bias, ushort16* __restrict__ h_hi,
    ushort16* __restrict__ h_lo, int n) {
  int wid = (blockIdx.x << 2) + (threadIdx.x >> 6);
  if (wid >= n) return;
  int lane = threadIdx.x & 63;
  long base2 = (long)wid * 64 + lane;  // uint32 units: 2 bf16 dims per lane

  uint32 selfv = hw2[base2];
  float acc0 = bfl(selfv), acc1 = bfh(selfv);

  int e0 = row_ptr[wid], e1 = row_ptr[wid + 1];
  int e = e0;
  for (; e + 8 <= e1; e += 8) {
    int s0 = col_src[e + 0], s1 = col_src[e + 1], s2 = col_src[e + 2], s3 = col_src[e + 3];
    int s4 = col_src[e + 4], s5 = col_src[e + 5], s6 = col_src[e + 6], s7 = col_src[e + 7];
    uint32 v0 = hw2[(long)s0 * 64 + lane], v1 = hw2[(long)s1 * 64 + lane];
    uint32 v2 = hw2[(long)s2 * 64 + lane], v3 = hw2[(long)s3 * 64 + lane];
    uint32 v4 = hw2[(long)s4 * 64 + lane], v5 = hw2[(long)s5 * 64 + lane];
    uint32 v6 = hw2[(long)s6 * 64 + lane], v7 = hw2[(long)s7 * 64 + lane];
    acc0 += ((bfl(v0) + bfl(v1)) + (bfl(v2) + bfl(v3))) +
            ((bfl(v4) + bfl(v5)) + (bfl(v6) + bfl(v7)));
    acc1 += ((bfh(v0) + bfh(v1)) + (bfh(v2) + bfh(v3))) +
            ((bfh(v4) + bfh(v5)) + (bfh(v6) + bfh(v7)));
  }
  for (; e < e1; ++e) {
    uint32 v = hw2[(long)col_src[e] * 64 + lane];
    acc0 += bfl(v);
    acc1 += bfh(v);
  }

  float dv = dinv[wid];
  float2 bv = ((const float2*)bias)[lane];
  float x0 = fmaf(acc0, dv, bv.x);
  float x1 = fmaf(acc1, dv, bv.y);
  float u0 = (x0 > 0.f) ? x0 : expm1f(x0);
  float u1 = (x1 > 0.f) ? x1 : expm1f(x1);

  uint32 hh = ((const uint32*)h_hi)[base2];
  uint32 hl = ((const uint32*)h_lo)[base2];
  float hv0 = bfl(hh) + bfl(hl) + u0;
  float hv1 = bfh(hh) + bfh(hl) + u1;
  ushort16 n0 = f2bf(hv0), n1 = f2bf(hv1);
  ((uint32*)h_hi)[base2] = (uint32)n0 | ((uint32)n1 << 16);
  float r0 = hv0 - bf2f(n0), r1 = hv1 - bf2f(n1);
  ((uint32*)h_lo)[base2] = (uint32)f2bf(r0) | ((uint32)f2bf(r1) << 16);
}

// ---------------- launch ----------------

extern "C" void kernel_launch(void* const* d_in, const int* in_sizes, int n_in,
                              void* d_out, int out_size, void* d_ws, size_t ws_size,
                              hipStream_t stream) {
  const float* x      = (const float*)d_in[0];
  const int*   ei     = (const int*)d_in[1];
  const float* conv_w = (const float*)d_in[2];
  const float* conv_b = (const float*)d_in[3];
  const float* lin_w  = (const float*)d_in[4];
  const float* lin_b  = (const float*)d_in[5];
  float* out = (float*)d_out;

  const int n = in_sizes[0] / 128;
  const int E = in_sizes[1] / 2;
  const int L = in_sizes[2] / (128 * 128);
  const int cn = L * 128 * 128;
  const int wn = cn + in_sizes[4];

  const int nT1 = (E + TILE1 - 1) / TILE1;        // pass-1 tiles
  const int nb1 = (n + 511) >> 9;                 // high buckets
  const int M = nb1 * nT1;                        // hist matrix size
  const int nbs = (M + 1023) / 1024;              // scan chunks

  char* p = (char*)d_ws;
  auto carve = [&](size_t bytes) {
    char* r = p;
    p += (bytes + 255) & ~(size_t)255;
    return r;
  };
  int*      histT   = (int*)carve((size_t)M * 4);
  int*      histS   = (int*)carve((size_t)M * 4);
  int*      bsums   = (int*)carve((size_t)nbs * 4);
  int*      keyT    = (int*)carve((size_t)E * 4);
  int*      srcT    = (int*)carve((size_t)E * 4);
  int*      col_src = (int*)carve((size_t)E * 4);
  int*      row_ptr = (int*)carve((size_t)(n + 1) * 4);
  float*    dinv    = (float*)carve((size_t)n * 4);
  ushort16* hw      = (ushort16*)carve((size_t)n * 128 * 2);
  __bf16*   h_hi    = (__bf16*)carve((size_t)n * 128 * 2);
  __bf16*   h_lo    = (__bf16*)carve((size_t)n * 128 * 2);
  __bf16*   w_hi    = (__bf16*)carve((size_t)wn * 2);
  __bf16*   w_lo    = (__bf16*)carve((size_t)wn * 2);
  __bf16*   lw_hi   = w_hi + cn;
  __bf16*   lw_lo   = w_lo + cn;

  // --- CSR build: MSD bucket sort, no global atomics ---
  hist1_kernel<<<nT1, 256, 0, stream>>>(ei, E, nT1, nb1, histT);
  scan1_kernel<<<nbs, 256, 0, stream>>>(histT, histS, bsums, M);
  scan2_kernel<<<1, 1, 0, stream>>>(bsums, nbs);
  scan_add_kernel<<<(M + 65535) / 65536 * 256, 256, 0, stream>>>(histS, bsums, M);
  scatter1_kernel<<<nT1, 256, 0, stream>>>(ei, E, nT1, nb1, histS, keyT, srcT);
  pass2_kernel<<<nb1, 256, 0, stream>>>(keyT, srcT, histS, nT1, nb1, E, n,
                                        col_src, row_ptr, dinv);
  finalize_rowptr_kernel<<<1, 1, 0, stream>>>(row_ptr, n, E);

  // --- weight + feature splits ---
  split_w_kernel<<<(wn + 255) / 256, 256, 0, stream>>>(conv_w, lin_w, cn, wn, w_hi, w_lo);
  init_h_kernel<<<2048, 256, 0, stream>>>(x, h_hi, h_lo, (long)n * 128);

  int gblocks = (n + 63) / 64;
  // out = x @ lin_w_block0^T + lin_b
  gemm_mfma_kernel<<<gblocks, 256, 0, stream>>>(h_hi, h_lo, lw_hi, lw_lo, 512,
                                                out, nullptr, nullptr, lin_b, 0, 3, n);
  for (int l = 0; l < L; ++l) {
    // hw = bf16((h @ Wl^T) * dinv[row])   (2-term split: output rounds to bf16 anyway)
    gemm_mfma_kernel<<<gblocks, 256, 0, stream>>>(
        h_hi, h_lo, w_hi + (size_t)l * 128 * 128, w_lo + (size_t)l * 128 * 128, 128,
        nullptr, hw, dinv, nullptr, 0, 2, n);
    // h = elu(dinv*(sum_in hw + hw_self) + b) + h
    aggregate_kernel<<<(n + 3) / 4, 256, 0, stream>>>(
        (const uint32*)hw, col_src, row_ptr, dinv, conv_b + (size_t)l * 128,
        (ushort16*)h_hi, (ushort16*)h_lo, n);
    // out += h @ lin_w_block_{l+1}^T
    gemm_mfma_kernel<<<gblocks, 256, 0, stream>>>(
        h_hi, h_lo, lw_hi + (size_t)(l + 1) * 128, lw_lo + (size_t)(l + 1) * 128, 512,
        out, nullptr, nullptr, nullptr, 1, 3, n);
  }
}

// Round 4
// 665.147 us; speedup vs baseline: 1.8794x; 1.5085x over previous
//
#include <hip/hip_runtime.h>
#include <hip/hip_bf16.h>
#include <math.h>

typedef __bf16 bf16x8 __attribute__((ext_vector_type(8)));
typedef float f32x4 __attribute__((ext_vector_type(4)));
typedef unsigned int uint32;
typedef unsigned short ushort16;

#define TILE1 2048  // edges per block in pass-1 kernels

__device__ inline float bfl(uint32 v) { return __uint_as_float(v << 16); }
__device__ inline float bfh(uint32 v) { return __uint_as_float(v & 0xffff0000u); }
__device__ inline ushort16 f2bf(float f) {
  __bf16 b = (__bf16)f;
  return __builtin_bit_cast(ushort16, b);
}
__device__ inline float bf2f(ushort16 u) { return __uint_as_float(((uint32)u) << 16); }

// ---------------- MSD bucket sort CSR build (no global atomics) ----------------

__global__ __launch_bounds__(256) void hist1_kernel(const int* __restrict__ ei, int E,
                                                    int nT1, int nb1, int* __restrict__ histT) {
  __shared__ int h[512];
  int t = threadIdx.x;
  for (int b = t; b < 512; b += 256) h[b] = 0;
  __syncthreads();
  int base = blockIdx.x * TILE1;
  int end = min(base + TILE1, E);
  for (int e = base + t; e < end; e += 256) {
    int d = ei[E + e];
    atomicAdd(&h[d >> 9], 1);
  }
  __syncthreads();
  for (int b = t; b < nb1; b += 256) histT[b * nT1 + blockIdx.x] = h[b];
}

__global__ __launch_bounds__(256) void scan1_kernel(const int* __restrict__ in,
                                                    int* __restrict__ out,
                                                    int* __restrict__ bsums, int m) {
  __shared__ int sdata[256];
  int t = threadIdx.x;
  int base = blockIdx.x * 1024;
  int v[4]; int s = 0;
#pragma unroll
  for (int c = 0; c < 4; ++c) {
    int idx = base + t * 4 + c;
    v[c] = (idx < m) ? in[idx] : 0;
    s += v[c];
  }
  sdata[t] = s;
  __syncthreads();
  for (int off = 1; off < 256; off <<= 1) {
    int y = (t >= off) ? sdata[t - off] : 0;
    __syncthreads();
    sdata[t] += y;
    __syncthreads();
  }
  int run = sdata[t] - s;
#pragma unroll
  for (int c = 0; c < 4; ++c) {
    int idx = base + t * 4 + c;
    if (idx < m) out[idx] = run;
    run += v[c];
  }
  if (t == 255) bsums[blockIdx.x] = sdata[255];
}

__global__ void scan2_kernel(int* bsums, int nb) {
  if (threadIdx.x == 0 && blockIdx.x == 0) {
    int run = 0;
    for (int i = 0; i < nb; ++i) { int v = bsums[i]; bsums[i] = run; run += v; }
  }
}

__global__ void scan_add_kernel(int* __restrict__ out, const int* __restrict__ bsums, int m) {
  int stride = gridDim.x * blockDim.x;
  for (int i = blockIdx.x * blockDim.x + threadIdx.x; i < m; i += stride)
    out[i] += bsums[i >> 10];
}

__global__ __launch_bounds__(256) void scatter1_kernel(const int* __restrict__ ei, int E,
                                                       int nT1, int nb1,
                                                       const int* __restrict__ histS,
                                                       int* __restrict__ keyT,
                                                       int* __restrict__ srcT) {
  __shared__ int base[512];
  int t = threadIdx.x;
  for (int b = t; b < nb1; b += 256) base[b] = histS[b * nT1 + blockIdx.x];
  __syncthreads();
  int s0 = blockIdx.x * TILE1;
  int end = min(s0 + TILE1, E);
  for (int e = s0 + t; e < end; e += 256) {
    int d = ei[E + e];
    int s = ei[e];
    int p = atomicAdd(&base[d >> 9], 1);  // LDS atomic
    keyT[p] = d;
    srcT[p] = s;
  }
}

__global__ __launch_bounds__(256) void pass2_kernel(
    const int* __restrict__ keyT, const int* __restrict__ srcT,
    const int* __restrict__ histS, int nT1, int nb1, int E, int n,
    int* __restrict__ col_src, int* __restrict__ row_ptr, float* __restrict__ dinv) {
  __shared__ int hist[512];
  __shared__ int offs[512];
  __shared__ int sdata[256];
  int b = blockIdx.x;
  int t = threadIdx.x;
  int bstart = histS[b * nT1];
  int bend = (b + 1 < nb1) ? histS[(b + 1) * nT1] : E;
  for (int i = t; i < 512; i += 256) hist[i] = 0;
  __syncthreads();
  for (int e = bstart + t; e < bend; e += 256)
    atomicAdd(&hist[keyT[e] & 511], 1);
  __syncthreads();
  int s2 = hist[2 * t] + hist[2 * t + 1];
  sdata[t] = s2;
  __syncthreads();
  for (int off = 1; off < 256; off <<= 1) {
    int y = (t >= off) ? sdata[t - off] : 0;
    __syncthreads();
    sdata[t] += y;
    __syncthreads();
  }
  int excl = sdata[t] - s2;
  offs[2 * t] = excl;
  offs[2 * t + 1] = excl + hist[2 * t];
  __syncthreads();
  for (int i = t; i < 512; i += 256) {
    int node = (b << 9) + i;
    if (node < n) {
      row_ptr[node] = bstart + offs[i];
      dinv[node] = rsqrtf((float)hist[i] + 1.0f);  // +1 self-loop
    }
  }
  __syncthreads();
  for (int e = bstart + t; e < bend; e += 256) {
    int d = keyT[e];
    int s = srcT[e];
    int p = atomicAdd(&offs[d & 511], 1);  // LDS atomic
    col_src[bstart + p] = s;
  }
}

__global__ void finalize_rowptr_kernel(int* row_ptr, int n, int E) {
  if (threadIdx.x == 0 && blockIdx.x == 0) row_ptr[n] = E;
}

// ---------------- bf16 prep ----------------

__global__ void cast_w_kernel(const float* __restrict__ cw, const float* __restrict__ lw,
                              int cn, int total, __bf16* __restrict__ whi) {
  int stride = gridDim.x * blockDim.x;
  for (int i = blockIdx.x * blockDim.x + threadIdx.x; i < total; i += stride) {
    float v = (i < cn) ? cw[i] : lw[i - cn];
    whi[i] = (__bf16)v;
  }
}

__global__ void init_h_kernel(const float* __restrict__ x, __bf16* __restrict__ h_hi,
                              __bf16* __restrict__ h_lo, long total) {
  long stride = (long)gridDim.x * blockDim.x;
  for (long i = blockIdx.x * (long)blockDim.x + threadIdx.x; i < total; i += stride) {
    float v = x[i];
    __bf16 hi = (__bf16)v;
    h_hi[i] = hi;
    h_lo[i] = (__bf16)(v - (float)hi);
  }
}

// ---------------- LDS-staged split-bf16 MFMA GEMM ----------------
// FUSED: C1 = bf16(rowscale*(A@W1^T)), C2 (+)= A@W2^T (+bias)   [two 128x128 B mats in LDS]
// else:  C2 (+)= A@W2^T (+bias)
// A = a_hi + a_lo ([n][128] bf16 pair). W row-major [128 cols][k], ldb1=128, ldb2 param.
// LDS layout per matrix: elem = col*128 + ((ch ^ (col&7))<<3) + j, ch = k-granule (8 elems).
// Frags: A row=l&15, k=(l>>4)*8+j (+32*kc); B col=l&15(+16nt); D col, row=(l>>4)*4+q.
template <bool FUSED>
__global__ __launch_bounds__(512) void gemm_kernel(
    const __bf16* __restrict__ a_hi, const __bf16* __restrict__ a_lo,
    const __bf16* __restrict__ w1, const __bf16* __restrict__ w2, int ldb2,
    ushort16* __restrict__ C1, const float* __restrict__ row_scale,
    float* __restrict__ C2, const float* __restrict__ bias, int accum, int n) {
  extern __shared__ __bf16 smem[];
  __bf16* s2 = FUSED ? (smem + 16384) : smem;
  int t = threadIdx.x;
  int wv = t >> 6;
  int l = t & 63;
  int r = l & 15;
  int g = l >> 4;
  int row0 = blockIdx.x * 128 + wv * 16;
  int arow = row0 + r;
  if (arow >= n) arow = n - 1;

  // A fragments -> registers (independent of LDS stage; overlaps)
  bf16x8 ah[4], al[4];
#pragma unroll
  for (int kc = 0; kc < 4; ++kc) {
    ah[kc] = *(const bf16x8*)(a_hi + (long)arow * 128 + kc * 32 + g * 8);
    al[kc] = *(const bf16x8*)(a_lo + (long)arow * 128 + kc * 32 + g * 8);
  }

  // stage B matrices into LDS (swizzled)
  if (FUSED) {
#pragma unroll
    for (int i = 0; i < 4; ++i) {
      int G = i * 512 + t;
      int col = G >> 4, ch = G & 15;
      bf16x8 v = *(const bf16x8*)(w1 + (long)col * 128 + ch * 8);
      *(bf16x8*)(smem + col * 128 + ((ch ^ (col & 7)) << 3)) = v;
    }
  }
#pragma unroll
  for (int i = 0; i < 4; ++i) {
    int G = i * 512 + t;
    int col = G >> 4, ch = G & 15;
    bf16x8 v = *(const bf16x8*)(w2 + (long)col * ldb2 + ch * 8);
    *(bf16x8*)(s2 + col * 128 + ((ch ^ (col & 7)) << 3)) = v;
  }
  __syncthreads();

  f32x4 acc1[8], acc2[8];
#pragma unroll
  for (int i = 0; i < 8; ++i) {
    acc1[i] = (f32x4){0.f, 0.f, 0.f, 0.f};
    acc2[i] = (f32x4){0.f, 0.f, 0.f, 0.f};
  }

#pragma unroll
  for (int kc = 0; kc < 4; ++kc) {
#pragma unroll
    for (int nt = 0; nt < 8; ++nt) {
      int col = nt * 16 + r;
      int goff = col * 128 + (((kc * 4 + g) ^ (col & 7)) << 3);
      if (FUSED) {
        bf16x8 f1 = *(const bf16x8*)(smem + goff);
        acc1[nt] = __builtin_amdgcn_mfma_f32_16x16x32_bf16(ah[kc], f1, acc1[nt], 0, 0, 0);
        acc1[nt] = __builtin_amdgcn_mfma_f32_16x16x32_bf16(al[kc], f1, acc1[nt], 0, 0, 0);
      }
      bf16x8 f2 = *(const bf16x8*)(s2 + goff);
      acc2[nt] = __builtin_amdgcn_mfma_f32_16x16x32_bf16(ah[kc], f2, acc2[nt], 0, 0, 0);
      acc2[nt] = __builtin_amdgcn_mfma_f32_16x16x32_bf16(al[kc], f2, acc2[nt], 0, 0, 0);
    }
  }

  int orow0 = row0 + g * 4;
  if (FUSED) {
    float rs[4];
#pragma unroll
    for (int q = 0; q < 4; ++q) {
      int gr = orow0 + q;
      rs[q] = (gr < n) ? row_scale[gr] : 0.f;
    }
#pragma unroll
    for (int nt = 0; nt < 8; ++nt) {
      int col = nt * 16 + r;
#pragma unroll
      for (int q = 0; q < 4; ++q) {
        int gr = orow0 + q;
        if (gr < n) C1[(long)gr * 128 + col] = f2bf(acc1[nt][q] * rs[q]);
      }
    }
  }
#pragma unroll
  for (int nt = 0; nt < 8; ++nt) {
    int col = nt * 16 + r;
    float bv = bias ? bias[col] : 0.f;
#pragma unroll
    for (int q = 0; q < 4; ++q) {
      int gr = orow0 + q;
      if (gr < n) {
        float* cp = C2 + (long)gr * 128 + col;
        float v = acc2[nt][q] + bv;
        if (accum) v += *cp;
        *cp = v;
      }
    }
  }
}

// ---------------- aggregate: one wave per node, bf16 hw gather ----------------
__global__ __launch_bounds__(256) void aggregate_kernel(
    const uint32* __restrict__ hw2, const int* __restrict__ col_src,
    const int* __restrict__ row_ptr, const float* __restrict__ dinv,
    const float* __restrict__ bias, ushort16* __restrict__ h_hi,
    ushort16* __restrict__ h_lo, int n) {
  int wid = (blockIdx.x << 2) + (threadIdx.x >> 6);
  if (wid >= n) return;
  int lane = threadIdx.x & 63;
  long base2 = (long)wid * 64 + lane;

  uint32 selfv = hw2[base2];
  float acc0 = bfl(selfv), acc1 = bfh(selfv);

  int e0 = row_ptr[wid], e1 = row_ptr[wid + 1];
  int e = e0;
  for (; e + 8 <= e1; e += 8) {
    int s0 = col_src[e + 0], s1 = col_src[e + 1], s2 = col_src[e + 2], s3 = col_src[e + 3];
    int s4 = col_src[e + 4], s5 = col_src[e + 5], s6 = col_src[e + 6], s7 = col_src[e + 7];
    uint32 v0 = hw2[(long)s0 * 64 + lane], v1 = hw2[(long)s1 * 64 + lane];
    uint32 v2 = hw2[(long)s2 * 64 + lane], v3 = hw2[(long)s3 * 64 + lane];
    uint32 v4 = hw2[(long)s4 * 64 + lane], v5 = hw2[(long)s5 * 64 + lane];
    uint32 v6 = hw2[(long)s6 * 64 + lane], v7 = hw2[(long)s7 * 64 + lane];
    acc0 += ((bfl(v0) + bfl(v1)) + (bfl(v2) + bfl(v3))) +
            ((bfl(v4) + bfl(v5)) + (bfl(v6) + bfl(v7)));
    acc1 += ((bfh(v0) + bfh(v1)) + (bfh(v2) + bfh(v3))) +
            ((bfh(v4) + bfh(v5)) + (bfh(v6) + bfh(v7)));
  }
  for (; e < e1; ++e) {
    uint32 v = hw2[(long)col_src[e] * 64 + lane];
    acc0 += bfl(v);
    acc1 += bfh(v);
  }

  float dv = dinv[wid];
  float2 bv = ((const float2*)bias)[lane];
  float x0 = fmaf(acc0, dv, bv.x);
  float x1 = fmaf(acc1, dv, bv.y);
  float u0 = (x0 > 0.f) ? x0 : expm1f(x0);
  float u1 = (x1 > 0.f) ? x1 : expm1f(x1);

  uint32 hh = ((const uint32*)h_hi)[base2];
  uint32 hl = ((const uint32*)h_lo)[base2];
  float hv0 = bfl(hh) + bfl(hl) + u0;
  float hv1 = bfh(hh) + bfh(hl) + u1;
  ushort16 n0 = f2bf(hv0), n1 = f2bf(hv1);
  ((uint32*)h_hi)[base2] = (uint32)n0 | ((uint32)n1 << 16);
  float r0 = hv0 - bf2f(n0), r1 = hv1 - bf2f(n1);
  ((uint32*)h_lo)[base2] = (uint32)f2bf(r0) | ((uint32)f2bf(r1) << 16);
}

// ---------------- launch ----------------

extern "C" void kernel_launch(void* const* d_in, const int* in_sizes, int n_in,
                              void* d_out, int out_size, void* d_ws, size_t ws_size,
                              hipStream_t stream) {
  const float* x      = (const float*)d_in[0];
  const int*   ei     = (const int*)d_in[1];
  const float* conv_w = (const float*)d_in[2];
  const float* conv_b = (const float*)d_in[3];
  const float* lin_w  = (const float*)d_in[4];
  const float* lin_b  = (const float*)d_in[5];
  float* out = (float*)d_out;

  const int n = in_sizes[0] / 128;
  const int E = in_sizes[1] / 2;
  const int L = in_sizes[2] / (128 * 128);
  const int cn = L * 128 * 128;
  const int wn = cn + in_sizes[4];

  const int nT1 = (E + TILE1 - 1) / TILE1;
  const int nb1 = (n + 511) >> 9;
  const int M = nb1 * nT1;
  const int nbs = (M + 1023) / 1024;

  char* p = (char*)d_ws;
  auto carve = [&](size_t bytes) {
    char* r = p;
    p += (bytes + 255) & ~(size_t)255;
    return r;
  };
  int*      histT   = (int*)carve((size_t)M * 4);
  int*      histS   = (int*)carve((size_t)M * 4);
  int*      bsums   = (int*)carve((size_t)nbs * 4);
  int*      keyT    = (int*)carve((size_t)E * 4);
  int*      srcT    = (int*)carve((size_t)E * 4);
  int*      col_src = (int*)carve((size_t)E * 4);
  int*      row_ptr = (int*)carve((size_t)(n + 1) * 4);
  float*    dinv    = (float*)carve((size_t)n * 4);
  ushort16* hw      = (ushort16*)carve((size_t)n * 128 * 2);
  __bf16*   h_hi    = (__bf16*)carve((size_t)n * 128 * 2);
  __bf16*   h_lo    = (__bf16*)carve((size_t)n * 128 * 2);
  __bf16*   w_hi    = (__bf16*)carve((size_t)wn * 2);
  __bf16*   lw_hi   = w_hi + cn;

  // --- CSR build: MSD bucket sort ---
  hist1_kernel<<<nT1, 256, 0, stream>>>(ei, E, nT1, nb1, histT);
  scan1_kernel<<<nbs, 256, 0, stream>>>(histT, histS, bsums, M);
  scan2_kernel<<<1, 1, 0, stream>>>(bsums, nbs);
  scan_add_kernel<<<(M + 65535) / 65536 * 256, 256, 0, stream>>>(histS, bsums, M);
  scatter1_kernel<<<nT1, 256, 0, stream>>>(ei, E, nT1, nb1, histS, keyT, srcT);
  pass2_kernel<<<nb1, 256, 0, stream>>>(keyT, srcT, histS, nT1, nb1, E, n,
                                        col_src, row_ptr, dinv);
  finalize_rowptr_kernel<<<1, 1, 0, stream>>>(row_ptr, n, E);

  // --- prep ---
  cast_w_kernel<<<(wn + 255) / 256, 256, 0, stream>>>(conv_w, lin_w, cn, wn, w_hi);
  init_h_kernel<<<2048, 256, 0, stream>>>(x, h_hi, h_lo, (long)n * 128);

  int gblocks = (n + 127) / 128;
  for (int l = 0; l < L; ++l) {
    // fused: hw = bf16((h_l @ Wl^T)*dinv) ; out (+)= h_l @ Bl^T (+lin_b at l=0)
    gemm_kernel<true><<<gblocks, 512, 65536, stream>>>(
        h_hi, h_lo, w_hi + (size_t)l * 128 * 128, lw_hi + (size_t)l * 128, 512,
        hw, dinv, out, (l == 0) ? lin_b : nullptr, (l == 0) ? 0 : 1, n);
    // h_{l+1} = elu(dinv*(sum_in hw + hw_self) + b) + h_l
    aggregate_kernel<<<(n + 3) / 4, 256, 0, stream>>>(
        (const uint32*)hw, col_src, row_ptr, dinv, conv_b + (size_t)l * 128,
        (ushort16*)h_hi, (ushort16*)h_lo, n);
  }
  // out += h_L @ B_L^T
  gemm_kernel<false><<<gblocks, 512, 32768, stream>>>(
      h_hi, h_lo, nullptr, lw_hi + (size_t)L * 128, 512,
      nullptr, nullptr, out, nullptr, 1, n);
}

// Round 5
// 533.654 us; speedup vs baseline: 2.3425x; 1.2464x over previous
//
#include <hip/hip_runtime.h>
#include <hip/hip_bf16.h>
#include <math.h>

typedef __bf16 bf16x8 __attribute__((ext_vector_type(8)));
typedef float f32x4 __attribute__((ext_vector_type(4)));
typedef unsigned int uint32;
typedef unsigned short ushort16;

#define TILE1 2048

__device__ inline float bfl(uint32 v) { return __uint_as_float(v << 16); }
__device__ inline float bfh(uint32 v) { return __uint_as_float(v & 0xffff0000u); }
__device__ inline ushort16 f2bf(float f) {
  __bf16 b = (__bf16)f;
  return __builtin_bit_cast(ushort16, b);
}
__device__ inline float bf2f(ushort16 u) { return __uint_as_float(((uint32)u) << 16); }

// ---------------- MSD bucket sort CSR build (no global atomics) ----------------
// pass1: bucket by dst>>9 (payload packed: (dst&511)<<20 | src); pass2: per-bucket
// 512-bin count+scan -> col_src, row_ptr, dinv.

__global__ __launch_bounds__(256) void hist1_kernel(const int* __restrict__ ei, int E,
                                                    int nT1, int nb1, int* __restrict__ histT) {
  __shared__ int h[512];
  int t = threadIdx.x;
  for (int b = t; b < 512; b += 256) h[b] = 0;
  __syncthreads();
  int base = blockIdx.x * TILE1;
  int end = min(base + TILE1, E);
  for (int e = base + t; e < end; e += 256) {
    int d = ei[E + e];
    atomicAdd(&h[d >> 9], 1);
  }
  __syncthreads();
  for (int b = t; b < nb1; b += 256) histT[b * nT1 + blockIdx.x] = h[b];
}

__global__ __launch_bounds__(256) void scan1_kernel(const int* __restrict__ in,
                                                    int* __restrict__ out,
                                                    int* __restrict__ bsums, int m) {
  __shared__ int sdata[256];
  int t = threadIdx.x;
  int base = blockIdx.x * 1024;
  int v[4]; int s = 0;
#pragma unroll
  for (int c = 0; c < 4; ++c) {
    int idx = base + t * 4 + c;
    v[c] = (idx < m) ? in[idx] : 0;
    s += v[c];
  }
  sdata[t] = s;
  __syncthreads();
  for (int off = 1; off < 256; off <<= 1) {
    int y = (t >= off) ? sdata[t - off] : 0;
    __syncthreads();
    sdata[t] += y;
    __syncthreads();
  }
  int run = sdata[t] - s;
#pragma unroll
  for (int c = 0; c < 4; ++c) {
    int idx = base + t * 4 + c;
    if (idx < m) out[idx] = run;
    run += v[c];
  }
  if (t == 255) bsums[blockIdx.x] = sdata[255];
}

// parallel block-scan (nb <= 256)
__global__ __launch_bounds__(256) void scan2_kernel(int* bsums, int nb) {
  __shared__ int sd[256];
  int t = threadIdx.x;
  int v = (t < nb) ? bsums[t] : 0;
  sd[t] = v;
  __syncthreads();
  for (int off = 1; off < 256; off <<= 1) {
    int y = (t >= off) ? sd[t - off] : 0;
    __syncthreads();
    sd[t] += y;
    __syncthreads();
  }
  if (t < nb) bsums[t] = sd[t] - v;
}

__global__ void scan_add_kernel(int* __restrict__ out, const int* __restrict__ bsums, int m) {
  int stride = gridDim.x * blockDim.x;
  for (int i = blockIdx.x * blockDim.x + threadIdx.x; i < m; i += stride)
    out[i] += bsums[i >> 10];
}

__global__ __launch_bounds__(256) void scatter1_kernel(const int* __restrict__ ei, int E,
                                                       int nT1, int nb1,
                                                       const int* __restrict__ histS,
                                                       uint32* __restrict__ pkT) {
  __shared__ int base[512];
  int t = threadIdx.x;
  for (int b = t; b < nb1; b += 256) base[b] = histS[b * nT1 + blockIdx.x];
  __syncthreads();
  int s0 = blockIdx.x * TILE1;
  int end = min(s0 + TILE1, E);
  for (int e = s0 + t; e < end; e += 256) {
    int d = ei[E + e];
    int s = ei[e];
    int p = atomicAdd(&base[d >> 9], 1);  // LDS atomic
    pkT[p] = ((uint32)(d & 511) << 20) | (uint32)s;  // n < 2^20
  }
}

__global__ __launch_bounds__(256) void pass2_kernel(
    const uint32* __restrict__ pkT, const int* __restrict__ histS, int nT1, int nb1,
    int E, int n, int* __restrict__ col_src, int* __restrict__ row_ptr,
    float* __restrict__ dinv) {
  __shared__ int hist[512];
  __shared__ int offs[512];
  __shared__ int sdata[256];
  int b = blockIdx.x;
  int t = threadIdx.x;
  int bstart = histS[b * nT1];
  int bend = (b + 1 < nb1) ? histS[(b + 1) * nT1] : E;
  for (int i = t; i < 512; i += 256) hist[i] = 0;
  __syncthreads();
  for (int e = bstart + t; e < bend; e += 256)
    atomicAdd(&hist[pkT[e] >> 20], 1);
  __syncthreads();
  int s2 = hist[2 * t] + hist[2 * t + 1];
  sdata[t] = s2;
  __syncthreads();
  for (int off = 1; off < 256; off <<= 1) {
    int y = (t >= off) ? sdata[t - off] : 0;
    __syncthreads();
    sdata[t] += y;
    __syncthreads();
  }
  int excl = sdata[t] - s2;
  offs[2 * t] = excl;
  offs[2 * t + 1] = excl + hist[2 * t];
  __syncthreads();
  for (int i = t; i < 512; i += 256) {
    int node = (b << 9) + i;
    if (node < n) {
      row_ptr[node] = bstart + offs[i];
      dinv[node] = rsqrtf((float)hist[i] + 1.0f);  // +1 self-loop
    }
  }
  __syncthreads();
  for (int e = bstart + t; e < bend; e += 256) {
    uint32 pk = pkT[e];
    int p = atomicAdd(&offs[pk >> 20], 1);  // LDS atomic
    col_src[bstart + p] = (int)(pk & 0xFFFFFu);
  }
}

__global__ void finalize_rowptr_kernel(int* row_ptr, int n, int E) {
  if (threadIdx.x == 0 && blockIdx.x == 0) row_ptr[n] = E;
}

// ---------------- prep ----------------

__global__ void cast_w_kernel(const float* __restrict__ cw, int total,
                              __bf16* __restrict__ whi) {
  int stride = gridDim.x * blockDim.x;
  for (int i = blockIdx.x * blockDim.x + threadIdx.x; i < total; i += stride)
    whi[i] = (__bf16)cw[i];
}

// CB[p][o][k] = bf16( sum_{l>=p} lin_w[o][l*128+k] ),  p in [0, parts)
__global__ void cumw_kernel(const float* __restrict__ lw, __bf16* __restrict__ CB,
                            int parts) {
  int idx = blockIdx.x * blockDim.x + threadIdx.x;
  if (idx >= parts * 16384) return;
  int p = idx >> 14, o = (idx >> 7) & 127, k = idx & 127;
  float s = 0.f;
  for (int l = p; l < parts; ++l) s += lw[o * (parts * 128) + l * 128 + k];
  CB[idx] = (__bf16)s;
}

__global__ void init_h_kernel(const float* __restrict__ x, __bf16* __restrict__ h_hi,
                              __bf16* __restrict__ h_lo, long total) {
  long stride = (long)gridDim.x * blockDim.x;
  for (long i = blockIdx.x * (long)blockDim.x + threadIdx.x; i < total; i += stride) {
    float v = x[i];
    __bf16 hi = (__bf16)v;
    h_hi[i] = hi;
    h_lo[i] = (__bf16)(v - (float)hi);
  }
}

// ---------------- conv GEMM: hw = bf16( (A @ W^T) * dinv[row] ) ----------------
// A = a_hi + a_lo ([n][128] bf16 pair), W [128][128] row-major (output-neuron rows).
// LDS swizzle: elem = col*128 + ((ch ^ (col&7))<<3) + j.
__global__ __launch_bounds__(512) void gemm_conv_kernel(
    const __bf16* __restrict__ a_hi, const __bf16* __restrict__ a_lo,
    const __bf16* __restrict__ w1, const float* __restrict__ row_scale,
    ushort16* __restrict__ C1, int n) {
  __shared__ __bf16 smem[16384];
  int t = threadIdx.x;
  int wv = t >> 6;
  int l = t & 63;
  int r = l & 15;
  int g = l >> 4;
  int row0 = blockIdx.x * 128 + wv * 16;
  int arow = row0 + r;
  if (arow >= n) arow = n - 1;

  bf16x8 ah[4], al[4];
#pragma unroll
  for (int kc = 0; kc < 4; ++kc) {
    ah[kc] = *(const bf16x8*)(a_hi + (long)arow * 128 + kc * 32 + g * 8);
    al[kc] = *(const bf16x8*)(a_lo + (long)arow * 128 + kc * 32 + g * 8);
  }
#pragma unroll
  for (int i = 0; i < 4; ++i) {
    int G = i * 512 + t;
    int col = G >> 4, ch = G & 15;
    bf16x8 v = *(const bf16x8*)(w1 + (long)col * 128 + ch * 8);
    *(bf16x8*)(smem + col * 128 + ((ch ^ (col & 7)) << 3)) = v;
  }
  __syncthreads();

  f32x4 acc[8];
#pragma unroll
  for (int i = 0; i < 8; ++i) acc[i] = (f32x4){0.f, 0.f, 0.f, 0.f};
#pragma unroll
  for (int kc = 0; kc < 4; ++kc) {
#pragma unroll
    for (int nt = 0; nt < 8; ++nt) {
      int col = nt * 16 + r;
      bf16x8 f1 = *(const bf16x8*)(smem + col * 128 + (((kc * 4 + g) ^ (col & 7)) << 3));
      acc[nt] = __builtin_amdgcn_mfma_f32_16x16x32_bf16(ah[kc], f1, acc[nt], 0, 0, 0);
      acc[nt] = __builtin_amdgcn_mfma_f32_16x16x32_bf16(al[kc], f1, acc[nt], 0, 0, 0);
    }
  }

  int orow0 = row0 + g * 4;
  float rs[4];
#pragma unroll
  for (int q = 0; q < 4; ++q) {
    int gr = orow0 + q;
    rs[q] = (gr < n) ? row_scale[gr] : 0.f;
  }
#pragma unroll
  for (int nt = 0; nt < 8; ++nt) {
    int col = nt * 16 + r;
#pragma unroll
    for (int q = 0; q < 4; ++q) {
      int gr = orow0 + q;
      if (gr < n) C1[(long)gr * 128 + col] = f2bf(acc[nt][q] * rs[q]);
    }
  }
}

// ---------------- final GEMM: out = x@CB0^T + e0@CB1^T + e1@CB2^T + e2@CB3^T + b ----------------
__global__ __launch_bounds__(512) void gemm_final_kernel(
    const float* __restrict__ x, const __bf16* __restrict__ eA,
    const __bf16* __restrict__ eB, const __bf16* __restrict__ eC,
    const __bf16* __restrict__ CB, float* __restrict__ out,
    const float* __restrict__ bias, int n) {
  __shared__ __bf16 smem[16384];
  int t = threadIdx.x;
  int wv = t >> 6;
  int l = t & 63;
  int r = l & 15;
  int g = l >> 4;
  int row0 = blockIdx.x * 128 + wv * 16;
  int arow = row0 + r;
  if (arow >= n) arow = n - 1;

  f32x4 acc[8];
#pragma unroll
  for (int i = 0; i < 8; ++i) acc[i] = (f32x4){0.f, 0.f, 0.f, 0.f};

  for (int p = 0; p < 4; ++p) {
    __syncthreads();  // previous part's LDS reads done
#pragma unroll
    for (int i = 0; i < 4; ++i) {
      int G = i * 512 + t;
      int col = G >> 4, ch = G & 15;
      bf16x8 v = *(const bf16x8*)(CB + p * 16384 + col * 128 + ch * 8);
      *(bf16x8*)(smem + col * 128 + ((ch ^ (col & 7)) << 3)) = v;
    }
    __syncthreads();

    bf16x8 af[4];
    if (p == 0) {
#pragma unroll
      for (int kc = 0; kc < 4; ++kc) {
        float4 f0 = *(const float4*)(x + (long)arow * 128 + kc * 32 + g * 8);
        float4 f1 = *(const float4*)(x + (long)arow * 128 + kc * 32 + g * 8 + 4);
        bf16x8 v;
        v[0] = (__bf16)f0.x; v[1] = (__bf16)f0.y; v[2] = (__bf16)f0.z; v[3] = (__bf16)f0.w;
        v[4] = (__bf16)f1.x; v[5] = (__bf16)f1.y; v[6] = (__bf16)f1.z; v[7] = (__bf16)f1.w;
        af[kc] = v;
      }
    } else {
      const __bf16* ep = (p == 1) ? eA : (p == 2) ? eB : eC;
#pragma unroll
      for (int kc = 0; kc < 4; ++kc)
        af[kc] = *(const bf16x8*)(ep + (long)arow * 128 + kc * 32 + g * 8);
    }
#pragma unroll
    for (int kc = 0; kc < 4; ++kc) {
#pragma unroll
      for (int nt = 0; nt < 8; ++nt) {
        int col = nt * 16 + r;
        bf16x8 f1 = *(const bf16x8*)(smem + col * 128 + (((kc * 4 + g) ^ (col & 7)) << 3));
        acc[nt] = __builtin_amdgcn_mfma_f32_16x16x32_bf16(af[kc], f1, acc[nt], 0, 0, 0);
      }
    }
  }

  int orow0 = row0 + g * 4;
#pragma unroll
  for (int nt = 0; nt < 8; ++nt) {
    int col = nt * 16 + r;
    float bv = bias[col];
#pragma unroll
    for (int q = 0; q < 4; ++q) {
      int gr = orow0 + q;
      if (gr < n) out[(long)gr * 128 + col] = acc[nt][q] + bv;
    }
  }
}

// ---------------- aggregate v2: half-wave per edge, dwordx2 gathers ----------------
// h = elu(dinv*(sum_in hw[src] + hw_self) + b) + h ; also stores e = elu(...) as bf16.
__global__ __launch_bounds__(256) void aggregate_kernel(
    const uint2* __restrict__ hw4, const int* __restrict__ col_src,
    const int* __restrict__ row_ptr, const float* __restrict__ dinv,
    const float* __restrict__ bias, uint2* __restrict__ h_hi4,
    uint2* __restrict__ h_lo4, uint2* __restrict__ e4, int n) {
  int wid = (blockIdx.x << 2) + (threadIdx.x >> 6);
  if (wid >= n) return;
  int lane = threadIdx.x & 63;
  int half = lane >> 5;   // 0: even edges, 1: odd edges
  int q = lane & 31;      // uint2 index within row (4 dims)
  long rbase = (long)wid * 32;

  uint2 selfv = hw4[rbase + q];

  float a0 = 0.f, a1 = 0.f, a2 = 0.f, a3 = 0.f;
  int eb = row_ptr[wid], ee = row_ptr[wid + 1];
  int e = eb;
  for (; e + 8 <= ee; e += 8) {
    int s0 = col_src[e + 0 + half];
    int s1 = col_src[e + 2 + half];
    int s2 = col_src[e + 4 + half];
    int s3 = col_src[e + 6 + half];
    uint2 v0 = hw4[(long)s0 * 32 + q];
    uint2 v1 = hw4[(long)s1 * 32 + q];
    uint2 v2 = hw4[(long)s2 * 32 + q];
    uint2 v3 = hw4[(long)s3 * 32 + q];
    a0 += (bfl(v0.x) + bfl(v1.x)) + (bfl(v2.x) + bfl(v3.x));
    a1 += (bfh(v0.x) + bfh(v1.x)) + (bfh(v2.x) + bfh(v3.x));
    a2 += (bfl(v0.y) + bfl(v1.y)) + (bfl(v2.y) + bfl(v3.y));
    a3 += (bfh(v0.y) + bfh(v1.y)) + (bfh(v2.y) + bfh(v3.y));
  }
  for (; e < ee; e += 2) {
    int idx = e + half;
    if (idx < ee) {
      int s = col_src[idx];
      uint2 v = hw4[(long)s * 32 + q];
      a0 += bfl(v.x); a1 += bfh(v.x); a2 += bfl(v.y); a3 += bfh(v.y);
    }
  }
  a0 += __shfl_down(a0, 32, 64);
  a1 += __shfl_down(a1, 32, 64);
  a2 += __shfl_down(a2, 32, 64);
  a3 += __shfl_down(a3, 32, 64);
  if (half == 0) {
    a0 += bfl(selfv.x); a1 += bfh(selfv.x); a2 += bfl(selfv.y); a3 += bfh(selfv.y);
    float dv = dinv[wid];
    float4 bv = ((const float4*)bias)[q];
    float x0 = fmaf(a0, dv, bv.x);
    float x1 = fmaf(a1, dv, bv.y);
    float x2 = fmaf(a2, dv, bv.z);
    float x3 = fmaf(a3, dv, bv.w);
    float u0 = (x0 > 0.f) ? x0 : expm1f(x0);
    float u1 = (x1 > 0.f) ? x1 : expm1f(x1);
    float u2 = (x2 > 0.f) ? x2 : expm1f(x2);
    float u3 = (x3 > 0.f) ? x3 : expm1f(x3);
    uint2 ev;
    ev.x = (uint32)f2bf(u0) | ((uint32)f2bf(u1) << 16);
    ev.y = (uint32)f2bf(u2) | ((uint32)f2bf(u3) << 16);
    e4[rbase + q] = ev;
    uint2 hh = h_hi4[rbase + q];
    uint2 hl = h_lo4[rbase + q];
    float hv0 = bfl(hh.x) + bfl(hl.x) + u0;
    float hv1 = bfh(hh.x) + bfh(hl.x) + u1;
    float hv2 = bfl(hh.y) + bfl(hl.y) + u2;
    float hv3 = bfh(hh.y) + bfh(hl.y) + u3;
    ushort16 n0 = f2bf(hv0), n1 = f2bf(hv1), n2 = f2bf(hv2), n3 = f2bf(hv3);
    uint2 nh;
    nh.x = (uint32)n0 | ((uint32)n1 << 16);
    nh.y = (uint32)n2 | ((uint32)n3 << 16);
    h_hi4[rbase + q] = nh;
    float r0 = hv0 - bf2f(n0), r1 = hv1 - bf2f(n1);
    float r2 = hv2 - bf2f(n2), r3 = hv3 - bf2f(n3);
    uint2 nl;
    nl.x = (uint32)f2bf(r0) | ((uint32)f2bf(r1) << 16);
    nl.y = (uint32)f2bf(r2) | ((uint32)f2bf(r3) << 16);
    h_lo4[rbase + q] = nl;
  }
}

// ---------------- launch ----------------

extern "C" void kernel_launch(void* const* d_in, const int* in_sizes, int n_in,
                              void* d_out, int out_size, void* d_ws, size_t ws_size,
                              hipStream_t stream) {
  const float* x      = (const float*)d_in[0];
  const int*   ei     = (const int*)d_in[1];
  const float* conv_w = (const float*)d_in[2];
  const float* conv_b = (const float*)d_in[3];
  const float* lin_w  = (const float*)d_in[4];
  const float* lin_b  = (const float*)d_in[5];
  float* out = (float*)d_out;

  const int n = in_sizes[0] / 128;
  const int E = in_sizes[1] / 2;
  const int L = in_sizes[2] / (128 * 128);
  const int cn = L * 128 * 128;

  const int nT1 = (E + TILE1 - 1) / TILE1;
  const int nb1 = (n + 511) >> 9;
  const int M = nb1 * nT1;
  const int nbs = (M + 1023) / 1024;

  char* p = (char*)d_ws;
  auto carve = [&](size_t bytes) {
    char* r = p;
    p += (bytes + 255) & ~(size_t)255;
    return r;
  };
  int*      histT   = (int*)carve((size_t)M * 4);
  int*      histS   = (int*)carve((size_t)M * 4);
  int*      bsums   = (int*)carve((size_t)nbs * 4);
  uint32*   pkT     = (uint32*)carve((size_t)E * 4);
  int*      col_src = (int*)carve((size_t)E * 4);
  int*      row_ptr = (int*)carve((size_t)(n + 1) * 4);
  float*    dinv    = (float*)carve((size_t)n * 4);
  ushort16* hw      = (ushort16*)carve((size_t)n * 128 * 2);
  __bf16*   h_hi    = (__bf16*)carve((size_t)n * 128 * 2);
  __bf16*   h_lo    = (__bf16*)carve((size_t)n * 128 * 2);
  __bf16*   e_all   = (__bf16*)carve((size_t)L * n * 128 * 2);
  __bf16*   w_conv  = (__bf16*)carve((size_t)cn * 2);
  __bf16*   CB      = (__bf16*)carve((size_t)(L + 1) * 16384 * 2);

  // --- CSR build ---
  hist1_kernel<<<nT1, 256, 0, stream>>>(ei, E, nT1, nb1, histT);
  scan1_kernel<<<nbs, 256, 0, stream>>>(histT, histS, bsums, M);
  scan2_kernel<<<1, 256, 0, stream>>>(bsums, nbs);
  scan_add_kernel<<<(M + 65535) / 65536 * 256, 256, 0, stream>>>(histS, bsums, M);
  scatter1_kernel<<<nT1, 256, 0, stream>>>(ei, E, nT1, nb1, histS, pkT);
  pass2_kernel<<<nb1, 256, 0, stream>>>(pkT, histS, nT1, nb1, E, n,
                                        col_src, row_ptr, dinv);
  finalize_rowptr_kernel<<<1, 1, 0, stream>>>(row_ptr, n, E);

  // --- prep ---
  cast_w_kernel<<<(cn + 255) / 256, 256, 0, stream>>>(conv_w, cn, w_conv);
  cumw_kernel<<<((L + 1) * 16384 + 255) / 256, 256, 0, stream>>>(lin_w, CB, L + 1);
  init_h_kernel<<<2048, 256, 0, stream>>>(x, h_hi, h_lo, (long)n * 128);

  int gblocks = (n + 127) / 128;
  for (int l = 0; l < L; ++l) {
    gemm_conv_kernel<<<gblocks, 512, 0, stream>>>(
        h_hi, h_lo, w_conv + (size_t)l * 128 * 128, dinv, hw, n);
    aggregate_kernel<<<(n + 3) / 4, 256, 0, stream>>>(
        (const uint2*)hw, col_src, row_ptr, dinv, conv_b + (size_t)l * 128,
        (uint2*)h_hi, (uint2*)h_lo, (uint2*)(e_all + (size_t)l * n * 128), n);
  }
  gemm_final_kernel<<<gblocks, 512, 0, stream>>>(
      x, e_all, e_all + (size_t)n * 128, e_all + (size_t)2 * n * 128,
      CB, out, lin_b, n);
}

// Round 6
// 516.780 us; speedup vs baseline: 2.4190x; 1.0327x over previous
//
#include <hip/hip_runtime.h>
#include <hip/hip_bf16.h>
#include <math.h>

typedef __bf16 bf16x8 __attribute__((ext_vector_type(8)));
typedef float f32x4 __attribute__((ext_vector_type(4)));
typedef unsigned int uint32;
typedef unsigned short ushort16;

#define TILE1 2048
#define TILES 16        // src tiles: src>>13 (8192 nodes = 2 MB bf16 hw slice)

__device__ inline float bfl(uint32 v) { return __uint_as_float(v << 16); }
__device__ inline float bfh(uint32 v) { return __uint_as_float(v & 0xffff0000u); }
__device__ inline ushort16 f2bf(float f) {
  __bf16 b = (__bf16)f;
  return __builtin_bit_cast(ushort16, b);
}
// bank-swizzle for stride-32 LDS walks (bijective within each 32-slot group)
__device__ inline int sw(int b) { return (b & ~31) | ((b + (b >> 5)) & 31); }

// split 8 contiguous floats into bf16 hi + lo fragments
__device__ inline void split8(const float* __restrict__ p, bf16x8& hi, bf16x8& lo) {
  float4 f0 = *(const float4*)p;
  float4 f1 = *(const float4*)(p + 4);
  float vv[8] = {f0.x, f0.y, f0.z, f0.w, f1.x, f1.y, f1.z, f1.w};
#pragma unroll
  for (int j = 0; j < 8; ++j) {
    __bf16 h = (__bf16)vv[j];
    hi[j] = h;
    lo[j] = (__bf16)(vv[j] - (float)h);
  }
}

// ---------------- MSD bucket sort CSR build (no global atomics) ----------------
// pass1: bucket by dst>>9, payload (dst&511)<<20 | src
// pass2: per bucket, 8192 bins = (dst&511)*16 + (src>>13) -> col_src sorted by
//        (dst, src-tile), plus row_ptr and dinv.

__global__ __launch_bounds__(256) void hist1_kernel(const int* __restrict__ ei, int E,
                                                    int nT1, int nb1, int* __restrict__ histT) {
  __shared__ int h[512];
  int t = threadIdx.x;
  for (int b = t; b < 512; b += 256) h[b] = 0;
  __syncthreads();
  int base = blockIdx.x * TILE1;
  int end = min(base + TILE1, E);
  for (int e = base + t; e < end; e += 256) {
    int d = ei[E + e];
    atomicAdd(&h[d >> 9], 1);
  }
  __syncthreads();
  for (int b = t; b < nb1; b += 256) histT[b * nT1 + blockIdx.x] = h[b];
}

__global__ __launch_bounds__(256) void scan1_kernel(const int* __restrict__ in,
                                                    int* __restrict__ out,
                                                    int* __restrict__ bsums, int m) {
  __shared__ int sdata[256];
  int t = threadIdx.x;
  int base = blockIdx.x * 1024;
  int v[4]; int s = 0;
#pragma unroll
  for (int c = 0; c < 4; ++c) {
    int idx = base + t * 4 + c;
    v[c] = (idx < m) ? in[idx] : 0;
    s += v[c];
  }
  sdata[t] = s;
  __syncthreads();
  for (int off = 1; off < 256; off <<= 1) {
    int y = (t >= off) ? sdata[t - off] : 0;
    __syncthreads();
    sdata[t] += y;
    __syncthreads();
  }
  int run = sdata[t] - s;
#pragma unroll
  for (int c = 0; c < 4; ++c) {
    int idx = base + t * 4 + c;
    if (idx < m) out[idx] = run;
    run += v[c];
  }
  if (t == 255) bsums[blockIdx.x] = sdata[255];
}

__global__ __launch_bounds__(256) void scan2_kernel(int* bsums, int nb) {
  __shared__ int sd[256];
  int t = threadIdx.x;
  int v = (t < nb) ? bsums[t] : 0;
  sd[t] = v;
  __syncthreads();
  for (int off = 1; off < 256; off <<= 1) {
    int y = (t >= off) ? sd[t - off] : 0;
    __syncthreads();
    sd[t] += y;
    __syncthreads();
  }
  if (t < nb) bsums[t] = sd[t] - v;
}

__global__ void scan_add_kernel(int* __restrict__ out, const int* __restrict__ bsums, int m) {
  int stride = gridDim.x * blockDim.x;
  for (int i = blockIdx.x * blockDim.x + threadIdx.x; i < m; i += stride)
    out[i] += bsums[i >> 10];
}

__global__ __launch_bounds__(256) void scatter1_kernel(const int* __restrict__ ei, int E,
                                                       int nT1, int nb1,
                                                       const int* __restrict__ histS,
                                                       uint32* __restrict__ pkT) {
  __shared__ int base[512];
  int t = threadIdx.x;
  for (int b = t; b < nb1; b += 256) base[b] = histS[b * nT1 + blockIdx.x];
  __syncthreads();
  int s0 = blockIdx.x * TILE1;
  int end = min(s0 + TILE1, E);
  for (int e = s0 + t; e < end; e += 256) {
    int d = ei[E + e];
    int s = ei[e];
    int p = atomicAdd(&base[d >> 9], 1);  // LDS atomic
    pkT[p] = ((uint32)(d & 511) << 20) | (uint32)s;  // n < 2^20
  }
}

__global__ __launch_bounds__(256) void pass2_kernel(
    const uint32* __restrict__ pkT, const int* __restrict__ histS, int nT1, int nb1,
    int E, int n, int* __restrict__ col_src, int* __restrict__ row_ptr,
    float* __restrict__ dinv) {
  __shared__ int offs[512 * TILES];
  __shared__ int sdata[256];
  int b = blockIdx.x;
  int t = threadIdx.x;
  int bstart = histS[b * nT1];
  int bend = (b + 1 < nb1) ? histS[(b + 1) * nT1] : E;
  int total = bend - bstart;
  for (int i = t; i < 512 * TILES; i += 256) offs[i] = 0;
  __syncthreads();
  for (int e = bstart + t; e < bend; e += 256) {
    uint32 pk = pkT[e];
    int bin = (int)((pk >> 20) << 4) | (int)((pk & 0xFFFFFu) >> 13);
    atomicAdd(&offs[sw(bin)], 1);
  }
  __syncthreads();
  // exclusive scan of 8192 bins (stride-32 serial chunks, bank-swizzled)
  int cbase = t * 32;
  int s = 0;
  for (int c = 0; c < 32; ++c) s += offs[sw(cbase + c)];
  sdata[t] = s;
  __syncthreads();
  for (int off = 1; off < 256; off <<= 1) {
    int y = (t >= off) ? sdata[t - off] : 0;
    __syncthreads();
    sdata[t] += y;
    __syncthreads();
  }
  int run = sdata[t] - s;
  for (int c = 0; c < 32; ++c) {
    int idx = sw(cbase + c);
    int v = offs[idx];
    offs[idx] = run;
    run += v;
  }
  __syncthreads();
  // row_ptr + dinv (degree = next dst-group start - this dst-group start)
  for (int i = t; i < 512; i += 256) {
    int node = (b << 9) + i;
    if (node < n) {
      int st = offs[sw(i << 4)];
      int nx = (i < 511) ? offs[sw((i + 1) << 4)] : total;
      row_ptr[node] = bstart + st;
      dinv[node] = rsqrtf((float)(nx - st) + 1.0f);  // +1 self-loop
    }
  }
  __syncthreads();
  for (int e = bstart + t; e < bend; e += 256) {
    uint32 pk = pkT[e];
    int src = (int)(pk & 0xFFFFFu);
    int bin = (int)((pk >> 20) << 4) | (src >> 13);
    int p = atomicAdd(&offs[sw(bin)], 1);  // LDS atomic cursor
    col_src[bstart + p] = src;
  }
}

__global__ void finalize_rowptr_kernel(int* row_ptr, int n, int E) {
  if (threadIdx.x == 0 && blockIdx.x == 0) row_ptr[n] = E;
}

// ---------------- prep ----------------

__global__ void cast_w_kernel(const float* __restrict__ cw, int total,
                              __bf16* __restrict__ whi) {
  int stride = gridDim.x * blockDim.x;
  for (int i = blockIdx.x * blockDim.x + threadIdx.x; i < total; i += stride)
    whi[i] = (__bf16)cw[i];
}

// CB[p][o][k] = bf16( sum_{l>=p} lin_w[o][l*128+k] )
__global__ void cumw_kernel(const float* __restrict__ lw, __bf16* __restrict__ CB,
                            int parts) {
  int idx = blockIdx.x * blockDim.x + threadIdx.x;
  if (idx >= parts * 16384) return;
  int p = idx >> 14, o = (idx >> 7) & 127, k = idx & 127;
  float s = 0.f;
  for (int l = p; l < parts; ++l) s += lw[o * (parts * 128) + l * 128 + k];
  CB[idx] = (__bf16)s;
}

// ---------------- conv GEMM: hw = bf16( (A @ W^T) * dinv[row] ), A fp32 ----------------
__global__ __launch_bounds__(512) void gemm_conv_kernel(
    const float* __restrict__ A, const __bf16* __restrict__ w1,
    const float* __restrict__ row_scale, ushort16* __restrict__ C1, int n) {
  __shared__ __bf16 smem[16384];
  int t = threadIdx.x;
  int wv = t >> 6;
  int l = t & 63;
  int r = l & 15;
  int g = l >> 4;
  int row0 = blockIdx.x * 128 + wv * 16;
  int arow = row0 + r;
  if (arow >= n) arow = n - 1;

  bf16x8 ah[4], al[4];
#pragma unroll
  for (int kc = 0; kc < 4; ++kc)
    split8(A + (long)arow * 128 + kc * 32 + g * 8, ah[kc], al[kc]);

#pragma unroll
  for (int i = 0; i < 4; ++i) {
    int G = i * 512 + t;
    int col = G >> 4, ch = G & 15;
    bf16x8 v = *(const bf16x8*)(w1 + (long)col * 128 + ch * 8);
    *(bf16x8*)(smem + col * 128 + ((ch ^ (col & 7)) << 3)) = v;
  }
  __syncthreads();

  f32x4 acc[8];
#pragma unroll
  for (int i = 0; i < 8; ++i) acc[i] = (f32x4){0.f, 0.f, 0.f, 0.f};
#pragma unroll
  for (int kc = 0; kc < 4; ++kc) {
#pragma unroll
    for (int nt = 0; nt < 8; ++nt) {
      int col = nt * 16 + r;
      bf16x8 f1 = *(const bf16x8*)(smem + col * 128 + (((kc * 4 + g) ^ (col & 7)) << 3));
      acc[nt] = __builtin_amdgcn_mfma_f32_16x16x32_bf16(ah[kc], f1, acc[nt], 0, 0, 0);
      acc[nt] = __builtin_amdgcn_mfma_f32_16x16x32_bf16(al[kc], f1, acc[nt], 0, 0, 0);
    }
  }

  int orow0 = row0 + g * 4;
  float rs[4];
#pragma unroll
  for (int q = 0; q < 4; ++q) {
    int gr = orow0 + q;
    rs[q] = (gr < n) ? row_scale[gr] : 0.f;
  }
#pragma unroll
  for (int nt = 0; nt < 8; ++nt) {
    int col = nt * 16 + r;
#pragma unroll
    for (int q = 0; q < 4; ++q) {
      int gr = orow0 + q;
      if (gr < n) C1[(long)gr * 128 + col] = f2bf(acc[nt][q] * rs[q]);
    }
  }
}

// ---------------- final GEMM: out = x@CB0^T + e0@CB1^T + e1@CB2^T + e2@CB3^T + b ----------------
__global__ __launch_bounds__(512) void gemm_final_kernel(
    const float* __restrict__ x, const __bf16* __restrict__ eA,
    const __bf16* __restrict__ eB, const __bf16* __restrict__ eC,
    const __bf16* __restrict__ CB, float* __restrict__ out,
    const float* __restrict__ bias, int n) {
  __shared__ __bf16 smem[16384];
  int t = threadIdx.x;
  int wv = t >> 6;
  int l = t & 63;
  int r = l & 15;
  int g = l >> 4;
  int row0 = blockIdx.x * 128 + wv * 16;
  int arow = row0 + r;
  if (arow >= n) arow = n - 1;

  f32x4 acc[8];
#pragma unroll
  for (int i = 0; i < 8; ++i) acc[i] = (f32x4){0.f, 0.f, 0.f, 0.f};

  for (int p = 0; p < 4; ++p) {
    __syncthreads();
#pragma unroll
    for (int i = 0; i < 4; ++i) {
      int G = i * 512 + t;
      int col = G >> 4, ch = G & 15;
      bf16x8 v = *(const bf16x8*)(CB + p * 16384 + col * 128 + ch * 8);
      *(bf16x8*)(smem + col * 128 + ((ch ^ (col & 7)) << 3)) = v;
    }
    __syncthreads();

    bf16x8 af[4];
    if (p == 0) {
#pragma unroll
      for (int kc = 0; kc < 4; ++kc) {
        bf16x8 hi, lo;
        split8(x + (long)arow * 128 + kc * 32 + g * 8, hi, lo);
        af[kc] = hi;
      }
    } else {
      const __bf16* ep = (p == 1) ? eA : (p == 2) ? eB : eC;
#pragma unroll
      for (int kc = 0; kc < 4; ++kc)
        af[kc] = *(const bf16x8*)(ep + (long)arow * 128 + kc * 32 + g * 8);
    }
#pragma unroll
    for (int kc = 0; kc < 4; ++kc) {
#pragma unroll
      for (int nt = 0; nt < 8; ++nt) {
        int col = nt * 16 + r;
        bf16x8 f1 = *(const bf16x8*)(smem + col * 128 + (((kc * 4 + g) ^ (col & 7)) << 3));
        acc[nt] = __builtin_amdgcn_mfma_f32_16x16x32_bf16(af[kc], f1, acc[nt], 0, 0, 0);
      }
    }
  }

  int orow0 = row0 + g * 4;
#pragma unroll
  for (int nt = 0; nt < 8; ++nt) {
    int col = nt * 16 + r;
    float bv = bias[col];
#pragma unroll
    for (int q = 0; q < 4; ++q) {
      int gr = orow0 + q;
      if (gr < n) out[(long)gr * 128 + col] = acc[nt][q] + bv;
    }
  }
}

// ---------------- aggregate: half-wave per edge, src-tile-sorted gather ----------------
// h_out = elu(dinv*(sum_in hw[src] + hw_self) + b) + h_in ; also e = elu(...) bf16.
__global__ __launch_bounds__(256) void aggregate_kernel(
    const uint2* __restrict__ hw4, const int* __restrict__ col_src,
    const int* __restrict__ row_ptr, const float* __restrict__ dinv,
    const float* __restrict__ bias, const float4* __restrict__ h_in,
    float4* __restrict__ h_out, uint2* __restrict__ e4, int n) {
  int wid = (blockIdx.x << 2) + (threadIdx.x >> 6);
  if (wid >= n) return;
  int lane = threadIdx.x & 63;
  int half = lane >> 5;   // 0: even edges, 1: odd edges
  int q = lane & 31;      // 4-dim group within row
  long rbase = (long)wid * 32;

  uint2 selfv = hw4[rbase + q];

  float a0 = 0.f, a1 = 0.f, a2 = 0.f, a3 = 0.f;
  int eb = row_ptr[wid], ee = row_ptr[wid + 1];
  int e = eb;
  for (; e + 8 <= ee; e += 8) {
    int s0 = col_src[e + 0 + half];
    int s1 = col_src[e + 2 + half];
    int s2 = col_src[e + 4 + half];
    int s3 = col_src[e + 6 + half];
    uint2 v0 = hw4[(long)s0 * 32 + q];
    uint2 v1 = hw4[(long)s1 * 32 + q];
    uint2 v2 = hw4[(long)s2 * 32 + q];
    uint2 v3 = hw4[(long)s3 * 32 + q];
    a0 += (bfl(v0.x) + bfl(v1.x)) + (bfl(v2.x) + bfl(v3.x));
    a1 += (bfh(v0.x) + bfh(v1.x)) + (bfh(v2.x) + bfh(v3.x));
    a2 += (bfl(v0.y) + bfl(v1.y)) + (bfl(v2.y) + bfl(v3.y));
    a3 += (bfh(v0.y) + bfh(v1.y)) + (bfh(v2.y) + bfh(v3.y));
  }
  for (; e < ee; e += 2) {
    int idx = e + half;
    if (idx < ee) {
      int s = col_src[idx];
      uint2 v = hw4[(long)s * 32 + q];
      a0 += bfl(v.x); a1 += bfh(v.x); a2 += bfl(v.y); a3 += bfh(v.y);
    }
  }
  a0 += __shfl_down(a0, 32, 64);
  a1 += __shfl_down(a1, 32, 64);
  a2 += __shfl_down(a2, 32, 64);
  a3 += __shfl_down(a3, 32, 64);
  if (half == 0) {
    a0 += bfl(selfv.x); a1 += bfh(selfv.x); a2 += bfl(selfv.y); a3 += bfh(selfv.y);
    float dv = dinv[wid];
    float4 bv = ((const float4*)bias)[q];
    float x0 = fmaf(a0, dv, bv.x);
    float x1 = fmaf(a1, dv, bv.y);
    float x2 = fmaf(a2, dv, bv.z);
    float x3 = fmaf(a3, dv, bv.w);
    float u0 = (x0 > 0.f) ? x0 : expm1f(x0);
    float u1 = (x1 > 0.f) ? x1 : expm1f(x1);
    float u2 = (x2 > 0.f) ? x2 : expm1f(x2);
    float u3 = (x3 > 0.f) ? x3 : expm1f(x3);
    uint2 ev;
    ev.x = (uint32)f2bf(u0) | ((uint32)f2bf(u1) << 16);
    ev.y = (uint32)f2bf(u2) | ((uint32)f2bf(u3) << 16);
    e4[rbase + q] = ev;
    float4 hv = h_in[rbase + q];
    hv.x += u0; hv.y += u1; hv.z += u2; hv.w += u3;
    h_out[rbase + q] = hv;
  }
}

// ---------------- launch ----------------

extern "C" void kernel_launch(void* const* d_in, const int* in_sizes, int n_in,
                              void* d_out, int out_size, void* d_ws, size_t ws_size,
                              hipStream_t stream) {
  const float* x      = (const float*)d_in[0];
  const int*   ei     = (const int*)d_in[1];
  const float* conv_w = (const float*)d_in[2];
  const float* conv_b = (const float*)d_in[3];
  const float* lin_w  = (const float*)d_in[4];
  const float* lin_b  = (const float*)d_in[5];
  float* out = (float*)d_out;

  const int n = in_sizes[0] / 128;
  const int E = in_sizes[1] / 2;
  const int L = in_sizes[2] / (128 * 128);
  const int cn = L * 128 * 128;

  const int nT1 = (E + TILE1 - 1) / TILE1;
  const int nb1 = (n + 511) >> 9;
  const int M = nb1 * nT1;
  const int nbs = (M + 1023) / 1024;

  char* p = (char*)d_ws;
  auto carve = [&](size_t bytes) {
    char* r = p;
    p += (bytes + 255) & ~(size_t)255;
    return r;
  };
  int*      histT   = (int*)carve((size_t)M * 4);
  int*      histS   = (int*)carve((size_t)M * 4);
  int*      bsums   = (int*)carve((size_t)nbs * 4);
  uint32*   pkT     = (uint32*)carve((size_t)E * 4);
  int*      col_src = (int*)carve((size_t)E * 4);
  int*      row_ptr = (int*)carve((size_t)(n + 1) * 4);
  float*    dinv    = (float*)carve((size_t)n * 4);
  ushort16* hw      = (ushort16*)carve((size_t)n * 128 * 2);
  float*    h       = (float*)carve((size_t)n * 128 * 4);
  __bf16*   e_all   = (__bf16*)carve((size_t)L * n * 128 * 2);
  __bf16*   w_conv  = (__bf16*)carve((size_t)cn * 2);
  __bf16*   CB      = (__bf16*)carve((size_t)(L + 1) * 16384 * 2);

  // --- CSR build ---
  hist1_kernel<<<nT1, 256, 0, stream>>>(ei, E, nT1, nb1, histT);
  scan1_kernel<<<nbs, 256, 0, stream>>>(histT, histS, bsums, M);
  scan2_kernel<<<1, 256, 0, stream>>>(bsums, nbs);
  scan_add_kernel<<<(M + 65535) / 65536 * 256, 256, 0, stream>>>(histS, bsums, M);
  scatter1_kernel<<<nT1, 256, 0, stream>>>(ei, E, nT1, nb1, histS, pkT);
  pass2_kernel<<<nb1, 256, 0, stream>>>(pkT, histS, nT1, nb1, E, n,
                                        col_src, row_ptr, dinv);
  finalize_rowptr_kernel<<<1, 1, 0, stream>>>(row_ptr, n, E);

  // --- prep ---
  cast_w_kernel<<<(cn + 255) / 256, 256, 0, stream>>>(conv_w, cn, w_conv);
  cumw_kernel<<<((L + 1) * 16384 + 255) / 256, 256, 0, stream>>>(lin_w, CB, L + 1);

  int gblocks = (n + 127) / 128;
  for (int l = 0; l < L; ++l) {
    const float* h_prev = (l == 0) ? x : h;
    gemm_conv_kernel<<<gblocks, 512, 0, stream>>>(
        h_prev, w_conv + (size_t)l * 128 * 128, dinv, hw, n);
    aggregate_kernel<<<(n + 3) / 4, 256, 0, stream>>>(
        (const uint2*)hw, col_src, row_ptr, dinv, conv_b + (size_t)l * 128,
        (const float4*)h_prev, (float4*)h, (uint2*)(e_all + (size_t)l * n * 128), n);
  }
  gemm_final_kernel<<<gblocks, 512, 0, stream>>>(
      x, e_all, e_all + (size_t)n * 128, e_all + (size_t)2 * n * 128,
      CB, out, lin_b, n);
}

// Round 7
// 498.167 us; speedup vs baseline: 2.5094x; 1.0374x over previous
//
#include <hip/hip_runtime.h>
#include <hip/hip_bf16.h>
#include <math.h>

typedef __bf16 bf16x8 __attribute__((ext_vector_type(8)));
typedef float f32x4 __attribute__((ext_vector_type(4)));
typedef unsigned int uint32;
typedef unsigned short ushort16;

#define TILE1 2048

__device__ inline float bfl(uint32 v) { return __uint_as_float(v << 16); }
__device__ inline float bfh(uint32 v) { return __uint_as_float(v & 0xffff0000u); }
__device__ inline ushort16 f2bf(float f) {
  __bf16 b = (__bf16)f;
  return __builtin_bit_cast(ushort16, b);
}

// ---------------- MSD bucket sort CSR build (no global atomics) ----------------
// pass1: bucket by dst>>9, payload (dst&511)<<20 | src
// pass2: per bucket, 512-bin count+scan -> col_src, row_ptr, dinv.

__global__ __launch_bounds__(256) void hist1_kernel(const int* __restrict__ ei, int E,
                                                    int nT1, int nb1, int* __restrict__ histT) {
  __shared__ int h[512];
  int t = threadIdx.x;
  for (int b = t; b < 512; b += 256) h[b] = 0;
  __syncthreads();
  int base = blockIdx.x * TILE1;
  int end = min(base + TILE1, E);
  for (int e = base + t; e < end; e += 256) {
    int d = ei[E + e];
    atomicAdd(&h[d >> 9], 1);
  }
  __syncthreads();
  for (int b = t; b < nb1; b += 256) histT[b * nT1 + blockIdx.x] = h[b];
}

__global__ __launch_bounds__(256) void scan1_kernel(const int* __restrict__ in,
                                                    int* __restrict__ out,
                                                    int* __restrict__ bsums, int m) {
  __shared__ int sdata[256];
  int t = threadIdx.x;
  int base = blockIdx.x * 1024;
  int v[4]; int s = 0;
#pragma unroll
  for (int c = 0; c < 4; ++c) {
    int idx = base + t * 4 + c;
    v[c] = (idx < m) ? in[idx] : 0;
    s += v[c];
  }
  sdata[t] = s;
  __syncthreads();
  for (int off = 1; off < 256; off <<= 1) {
    int y = (t >= off) ? sdata[t - off] : 0;
    __syncthreads();
    sdata[t] += y;
    __syncthreads();
  }
  int run = sdata[t] - s;
#pragma unroll
  for (int c = 0; c < 4; ++c) {
    int idx = base + t * 4 + c;
    if (idx < m) out[idx] = run;
    run += v[c];
  }
  if (t == 255) bsums[blockIdx.x] = sdata[255];
}

__global__ __launch_bounds__(256) void scan2_kernel(int* bsums, int nb) {
  __shared__ int sd[256];
  int t = threadIdx.x;
  int v = (t < nb) ? bsums[t] : 0;
  sd[t] = v;
  __syncthreads();
  for (int off = 1; off < 256; off <<= 1) {
    int y = (t >= off) ? sd[t - off] : 0;
    __syncthreads();
    sd[t] += y;
    __syncthreads();
  }
  if (t < nb) bsums[t] = sd[t] - v;
}

__global__ void scan_add_kernel(int* __restrict__ out, const int* __restrict__ bsums, int m) {
  int stride = gridDim.x * blockDim.x;
  for (int i = blockIdx.x * blockDim.x + threadIdx.x; i < m; i += stride)
    out[i] += bsums[i >> 10];
}

__global__ __launch_bounds__(256) void scatter1_kernel(const int* __restrict__ ei, int E,
                                                       int nT1, int nb1,
                                                       const int* __restrict__ histS,
                                                       uint32* __restrict__ pkT) {
  __shared__ int base[512];
  int t = threadIdx.x;
  for (int b = t; b < nb1; b += 256) base[b] = histS[b * nT1 + blockIdx.x];
  __syncthreads();
  int s0 = blockIdx.x * TILE1;
  int end = min(s0 + TILE1, E);
  for (int e = s0 + t; e < end; e += 256) {
    int d = ei[E + e];
    int s = ei[e];
    int p = atomicAdd(&base[d >> 9], 1);  // LDS atomic
    pkT[p] = ((uint32)(d & 511) << 20) | (uint32)s;  // n < 2^20
  }
}

__global__ __launch_bounds__(256) void pass2_kernel(
    const uint32* __restrict__ pkT, const int* __restrict__ histS, int nT1, int nb1,
    int E, int n, int* __restrict__ col_src, int* __restrict__ row_ptr,
    float* __restrict__ dinv) {
  __shared__ int hist[512];
  __shared__ int offs[512];
  __shared__ int sdata[256];
  int b = blockIdx.x;
  int t = threadIdx.x;
  int bstart = histS[b * nT1];
  int bend = (b + 1 < nb1) ? histS[(b + 1) * nT1] : E;
  for (int i = t; i < 512; i += 256) hist[i] = 0;
  __syncthreads();
  for (int e = bstart + t; e < bend; e += 256)
    atomicAdd(&hist[pkT[e] >> 20], 1);
  __syncthreads();
  int s2 = hist[2 * t] + hist[2 * t + 1];
  sdata[t] = s2;
  __syncthreads();
  for (int off = 1; off < 256; off <<= 1) {
    int y = (t >= off) ? sdata[t - off] : 0;
    __syncthreads();
    sdata[t] += y;
    __syncthreads();
  }
  int excl = sdata[t] - s2;
  offs[2 * t] = excl;
  offs[2 * t + 1] = excl + hist[2 * t];
  __syncthreads();
  for (int i = t; i < 512; i += 256) {
    int node = (b << 9) + i;
    if (node < n) {
      row_ptr[node] = bstart + offs[i];
      dinv[node] = rsqrtf((float)hist[i] + 1.0f);  // +1 self-loop
    }
  }
  __syncthreads();
  for (int e = bstart + t; e < bend; e += 256) {
    uint32 pk = pkT[e];
    int p = atomicAdd(&offs[pk >> 20], 1);  // LDS atomic cursor
    col_src[bstart + p] = (int)(pk & 0xFFFFFu);
  }
}

__global__ void finalize_rowptr_kernel(int* row_ptr, int n, int E) {
  if (threadIdx.x == 0 && blockIdx.x == 0) row_ptr[n] = E;
}

// ---------------- prep ----------------

__global__ void cast_w_kernel(const float* __restrict__ cw, int total,
                              __bf16* __restrict__ whi) {
  int stride = gridDim.x * blockDim.x;
  for (int i = blockIdx.x * blockDim.x + threadIdx.x; i < total; i += stride)
    whi[i] = (__bf16)cw[i];
}

// CB[p][o][k] = bf16( sum_{l>=p} lin_w[o][l*128+k] )
__global__ void cumw_kernel(const float* __restrict__ lw, __bf16* __restrict__ CB,
                            int parts) {
  int idx = blockIdx.x * blockDim.x + threadIdx.x;
  if (idx >= parts * 16384) return;
  int p = idx >> 14, o = (idx >> 7) & 127, k = idx & 127;
  float s = 0.f;
  for (int l = p; l < parts; ++l) s += lw[o * (parts * 128) + l * 128 + k];
  CB[idx] = (__bf16)s;
}

// ---------------- conv GEMM: hw = bf16( ((x+e0+e1) @ W^T) * dinv[row] ) ----------------
// A built on the fly: fp32 x row + optional bf16 e rows, split to bf16 hi/lo.
__global__ __launch_bounds__(512) void gemm_conv_kernel(
    const float* __restrict__ X, const __bf16* __restrict__ E0,
    const __bf16* __restrict__ E1, const __bf16* __restrict__ w1,
    const float* __restrict__ row_scale, ushort16* __restrict__ C1, int n) {
  __shared__ __bf16 smem[16384];
  int t = threadIdx.x;
  int wv = t >> 6;
  int l = t & 63;
  int r = l & 15;
  int g = l >> 4;
  int row0 = blockIdx.x * 128 + wv * 16;
  int arow = row0 + r;
  if (arow >= n) arow = n - 1;

  bf16x8 ah[4], al[4];
#pragma unroll
  for (int kc = 0; kc < 4; ++kc) {
    long off = (long)arow * 128 + kc * 32 + g * 8;
    float4 f0 = *(const float4*)(X + off);
    float4 f1 = *(const float4*)(X + off + 4);
    float vv[8] = {f0.x, f0.y, f0.z, f0.w, f1.x, f1.y, f1.z, f1.w};
    if (E0) {
      bf16x8 tv = *(const bf16x8*)(E0 + off);
#pragma unroll
      for (int j = 0; j < 8; ++j) vv[j] += (float)tv[j];
    }
    if (E1) {
      bf16x8 tv = *(const bf16x8*)(E1 + off);
#pragma unroll
      for (int j = 0; j < 8; ++j) vv[j] += (float)tv[j];
    }
#pragma unroll
    for (int j = 0; j < 8; ++j) {
      __bf16 hb = (__bf16)vv[j];
      ah[kc][j] = hb;
      al[kc][j] = (__bf16)(vv[j] - (float)hb);
    }
  }

#pragma unroll
  for (int i = 0; i < 4; ++i) {
    int G = i * 512 + t;
    int col = G >> 4, ch = G & 15;
    bf16x8 v = *(const bf16x8*)(w1 + (long)col * 128 + ch * 8);
    *(bf16x8*)(smem + col * 128 + ((ch ^ (col & 7)) << 3)) = v;
  }
  __syncthreads();

  f32x4 acc[8];
#pragma unroll
  for (int i = 0; i < 8; ++i) acc[i] = (f32x4){0.f, 0.f, 0.f, 0.f};
#pragma unroll
  for (int kc = 0; kc < 4; ++kc) {
#pragma unroll
    for (int nt = 0; nt < 8; ++nt) {
      int col = nt * 16 + r;
      bf16x8 f1 = *(const bf16x8*)(smem + col * 128 + (((kc * 4 + g) ^ (col & 7)) << 3));
      acc[nt] = __builtin_amdgcn_mfma_f32_16x16x32_bf16(ah[kc], f1, acc[nt], 0, 0, 0);
      acc[nt] = __builtin_amdgcn_mfma_f32_16x16x32_bf16(al[kc], f1, acc[nt], 0, 0, 0);
    }
  }

  int orow0 = row0 + g * 4;
  float rs[4];
#pragma unroll
  for (int q = 0; q < 4; ++q) {
    int gr = orow0 + q;
    rs[q] = (gr < n) ? row_scale[gr] : 0.f;
  }
#pragma unroll
  for (int nt = 0; nt < 8; ++nt) {
    int col = nt * 16 + r;
#pragma unroll
    for (int q = 0; q < 4; ++q) {
      int gr = orow0 + q;
      if (gr < n) C1[(long)gr * 128 + col] = f2bf(acc[nt][q] * rs[q]);
    }
  }
}

// ---------------- final GEMM: out = x@CB0^T + e0@CB1^T + e1@CB2^T + e2@CB3^T + b ----------------
__global__ __launch_bounds__(512) void gemm_final_kernel(
    const float* __restrict__ x, const __bf16* __restrict__ eA,
    const __bf16* __restrict__ eB, const __bf16* __restrict__ eC,
    const __bf16* __restrict__ CB, float* __restrict__ out,
    const float* __restrict__ bias, int n) {
  __shared__ __bf16 smem[16384];
  int t = threadIdx.x;
  int wv = t >> 6;
  int l = t & 63;
  int r = l & 15;
  int g = l >> 4;
  int row0 = blockIdx.x * 128 + wv * 16;
  int arow = row0 + r;
  if (arow >= n) arow = n - 1;

  f32x4 acc[8];
#pragma unroll
  for (int i = 0; i < 8; ++i) acc[i] = (f32x4){0.f, 0.f, 0.f, 0.f};

  for (int p = 0; p < 4; ++p) {
    __syncthreads();
#pragma unroll
    for (int i = 0; i < 4; ++i) {
      int G = i * 512 + t;
      int col = G >> 4, ch = G & 15;
      bf16x8 v = *(const bf16x8*)(CB + p * 16384 + col * 128 + ch * 8);
      *(bf16x8*)(smem + col * 128 + ((ch ^ (col & 7)) << 3)) = v;
    }
    __syncthreads();

    bf16x8 af[4];
    if (p == 0) {
#pragma unroll
      for (int kc = 0; kc < 4; ++kc) {
        long off = (long)arow * 128 + kc * 32 + g * 8;
        float4 f0 = *(const float4*)(x + off);
        float4 f1 = *(const float4*)(x + off + 4);
        bf16x8 v;
        v[0] = (__bf16)f0.x; v[1] = (__bf16)f0.y; v[2] = (__bf16)f0.z; v[3] = (__bf16)f0.w;
        v[4] = (__bf16)f1.x; v[5] = (__bf16)f1.y; v[6] = (__bf16)f1.z; v[7] = (__bf16)f1.w;
        af[kc] = v;
      }
    } else {
      const __bf16* ep = (p == 1) ? eA : (p == 2) ? eB : eC;
#pragma unroll
      for (int kc = 0; kc < 4; ++kc)
        af[kc] = *(const bf16x8*)(ep + (long)arow * 128 + kc * 32 + g * 8);
    }
#pragma unroll
    for (int kc = 0; kc < 4; ++kc) {
#pragma unroll
      for (int nt = 0; nt < 8; ++nt) {
        int col = nt * 16 + r;
        bf16x8 f1 = *(const bf16x8*)(smem + col * 128 + (((kc * 4 + g) ^ (col & 7)) << 3));
        acc[nt] = __builtin_amdgcn_mfma_f32_16x16x32_bf16(af[kc], f1, acc[nt], 0, 0, 0);
      }
    }
  }

  int orow0 = row0 + g * 4;
#pragma unroll
  for (int nt = 0; nt < 8; ++nt) {
    int col = nt * 16 + r;
    float bv = bias[col];
#pragma unroll
    for (int q = 0; q < 4; ++q) {
      int gr = orow0 + q;
      if (gr < n) out[(long)gr * 128 + col] = acc[nt][q] + bv;
    }
  }
}

// ---------------- aggregate: half-wave per edge, pure gather -> e (bf16) ----------------
// e = elu(dinv[i]*(sum_in hw[src] + hw[i]) + b)   (no h stream)
__global__ __launch_bounds__(256) void aggregate_kernel(
    const uint2* __restrict__ hw4, const int* __restrict__ col_src,
    const int* __restrict__ row_ptr, const float* __restrict__ dinv,
    const float* __restrict__ bias, uint2* __restrict__ e4, int n) {
  int wid = (blockIdx.x << 2) + (threadIdx.x >> 6);
  if (wid >= n) return;
  int lane = threadIdx.x & 63;
  int half = lane >> 5;   // 0: even edges, 1: odd edges
  int q = lane & 31;      // 4-dim group within row
  long rbase = (long)wid * 32;

  uint2 selfv = hw4[rbase + q];

  float a0 = 0.f, a1 = 0.f, a2 = 0.f, a3 = 0.f;
  int eb = row_ptr[wid], ee = row_ptr[wid + 1];
  int e = eb;
  for (; e + 16 <= ee; e += 16) {
    int s[8];
#pragma unroll
    for (int u = 0; u < 8; ++u) s[u] = col_src[e + 2 * u + half];
    uint2 v[8];
#pragma unroll
    for (int u = 0; u < 8; ++u) v[u] = hw4[(long)s[u] * 32 + q];
#pragma unroll
    for (int u = 0; u < 8; ++u) {
      a0 += bfl(v[u].x); a1 += bfh(v[u].x);
      a2 += bfl(v[u].y); a3 += bfh(v[u].y);
    }
  }
  for (; e + 8 <= ee; e += 8) {
    int s0 = col_src[e + 0 + half], s1 = col_src[e + 2 + half];
    int s2 = col_src[e + 4 + half], s3 = col_src[e + 6 + half];
    uint2 v0 = hw4[(long)s0 * 32 + q], v1 = hw4[(long)s1 * 32 + q];
    uint2 v2 = hw4[(long)s2 * 32 + q], v3 = hw4[(long)s3 * 32 + q];
    a0 += (bfl(v0.x) + bfl(v1.x)) + (bfl(v2.x) + bfl(v3.x));
    a1 += (bfh(v0.x) + bfh(v1.x)) + (bfh(v2.x) + bfh(v3.x));
    a2 += (bfl(v0.y) + bfl(v1.y)) + (bfl(v2.y) + bfl(v3.y));
    a3 += (bfh(v0.y) + bfh(v1.y)) + (bfh(v2.y) + bfh(v3.y));
  }
  for (; e < ee; e += 2) {
    int idx = e + half;
    if (idx < ee) {
      int s = col_src[idx];
      uint2 v = hw4[(long)s * 32 + q];
      a0 += bfl(v.x); a1 += bfh(v.x); a2 += bfl(v.y); a3 += bfh(v.y);
    }
  }
  a0 += __shfl_down(a0, 32, 64);
  a1 += __shfl_down(a1, 32, 64);
  a2 += __shfl_down(a2, 32, 64);
  a3 += __shfl_down(a3, 32, 64);
  if (half == 0) {
    a0 += bfl(selfv.x); a1 += bfh(selfv.x); a2 += bfl(selfv.y); a3 += bfh(selfv.y);
    float dv = dinv[wid];
    float4 bv = ((const float4*)bias)[q];
    float x0 = fmaf(a0, dv, bv.x);
    float x1 = fmaf(a1, dv, bv.y);
    float x2 = fmaf(a2, dv, bv.z);
    float x3 = fmaf(a3, dv, bv.w);
    float u0 = (x0 > 0.f) ? x0 : expm1f(x0);
    float u1 = (x1 > 0.f) ? x1 : expm1f(x1);
    float u2 = (x2 > 0.f) ? x2 : expm1f(x2);
    float u3 = (x3 > 0.f) ? x3 : expm1f(x3);
    uint2 ev;
    ev.x = (uint32)f2bf(u0) | ((uint32)f2bf(u1) << 16);
    ev.y = (uint32)f2bf(u2) | ((uint32)f2bf(u3) << 16);
    e4[rbase + q] = ev;
  }
}

// ---------------- launch ----------------

extern "C" void kernel_launch(void* const* d_in, const int* in_sizes, int n_in,
                              void* d_out, int out_size, void* d_ws, size_t ws_size,
                              hipStream_t stream) {
  const float* x      = (const float*)d_in[0];
  const int*   ei     = (const int*)d_in[1];
  const float* conv_w = (const float*)d_in[2];
  const float* conv_b = (const float*)d_in[3];
  const float* lin_w  = (const float*)d_in[4];
  const float* lin_b  = (const float*)d_in[5];
  float* out = (float*)d_out;

  const int n = in_sizes[0] / 128;
  const int E = in_sizes[1] / 2;
  const int L = in_sizes[2] / (128 * 128);
  const int cn = L * 128 * 128;

  const int nT1 = (E + TILE1 - 1) / TILE1;
  const int nb1 = (n + 511) >> 9;
  const int M = nb1 * nT1;
  const int nbs = (M + 1023) / 1024;

  char* p = (char*)d_ws;
  auto carve = [&](size_t bytes) {
    char* r = p;
    p += (bytes + 255) & ~(size_t)255;
    return r;
  };
  int*      histT   = (int*)carve((size_t)M * 4);
  int*      histS   = (int*)carve((size_t)M * 4);
  int*      bsums   = (int*)carve((size_t)nbs * 4);
  uint32*   pkT     = (uint32*)carve((size_t)E * 4);
  int*      col_src = (int*)carve((size_t)E * 4);
  int*      row_ptr = (int*)carve((size_t)(n + 1) * 4);
  float*    dinv    = (float*)carve((size_t)n * 4);
  ushort16* hw      = (ushort16*)carve((size_t)n * 128 * 2);
  __bf16*   e_all   = (__bf16*)carve((size_t)L * n * 128 * 2);
  __bf16*   w_conv  = (__bf16*)carve((size_t)cn * 2);
  __bf16*   CB      = (__bf16*)carve((size_t)(L + 1) * 16384 * 2);

  __bf16* e0 = e_all;
  __bf16* e1 = e_all + (size_t)n * 128;
  __bf16* e2 = e_all + (size_t)2 * n * 128;

  // --- CSR build ---
  hist1_kernel<<<nT1, 256, 0, stream>>>(ei, E, nT1, nb1, histT);
  scan1_kernel<<<nbs, 256, 0, stream>>>(histT, histS, bsums, M);
  scan2_kernel<<<1, 256, 0, stream>>>(bsums, nbs);
  scan_add_kernel<<<(M + 65535) / 65536 * 256, 256, 0, stream>>>(histS, bsums, M);
  scatter1_kernel<<<nT1, 256, 0, stream>>>(ei, E, nT1, nb1, histS, pkT);
  pass2_kernel<<<nb1, 256, 0, stream>>>(pkT, histS, nT1, nb1, E, n,
                                        col_src, row_ptr, dinv);
  finalize_rowptr_kernel<<<1, 1, 0, stream>>>(row_ptr, n, E);

  // --- prep ---
  cast_w_kernel<<<(cn + 255) / 256, 256, 0, stream>>>(conv_w, cn, w_conv);
  cumw_kernel<<<((L + 1) * 16384 + 255) / 256, 256, 0, stream>>>(lin_w, CB, L + 1);

  int gblocks = (n + 127) / 128;
  for (int l = 0; l < L; ++l) {
    // hw = bf16( ((x + e0.. ) @ Wl^T) * dinv[row] )
    gemm_conv_kernel<<<gblocks, 512, 0, stream>>>(
        x, (l >= 1) ? e0 : nullptr, (l >= 2) ? e1 : nullptr,
        w_conv + (size_t)l * 128 * 128, dinv, hw, n);
    // e_l = elu(dinv*(sum_in hw + hw_self) + b)
    aggregate_kernel<<<(n + 3) / 4, 256, 0, stream>>>(
        (const uint2*)hw, col_src, row_ptr, dinv, conv_b + (size_t)l * 128,
        (uint2*)(e_all + (size_t)l * n * 128), n);
  }
  gemm_final_kernel<<<gblocks, 512, 0, stream>>>(
      x, e0, e1, e2, CB, out, lin_b, n);
}